// Round 9
// baseline (569.702 us; speedup 1.0000x reference)
//
#include <hip/hip_runtime.h>
#include <hip/hip_bf16.h>
#include <math.h>

typedef __hip_bfloat16 bf16;
typedef unsigned short u16;
using frag8 = __attribute__((ext_vector_type(8))) short;   // 8 bf16 = 4 VGPRs
using f32x4 = __attribute__((ext_vector_type(4))) float;   // MFMA accumulator
using u16x8 = __attribute__((ext_vector_type(8))) unsigned short;

// Problem constants
#define Bn      32768
#define IN_DIM  256
#define N_HDIM  512
#define QDIM    1024
#define N_EMBD  256

// Output layout (float32): recon [B*256] | khot [B*1024] | scalar [1] | k [B]
#define OUT_KHOT_OFF   ((size_t)Bn * IN_DIM)
#define OUT_SCALAR_OFF (OUT_KHOT_OFF + (size_t)Bn * QDIM)
#define OUT_K_OFF      (OUT_SCALAR_OFF + 1)

// Workspace layout (bytes)
#define WS_WK1    0                                   // 512x1280 bf16 (full)
#define WS_WE2    (WS_WK1 + 512*1280*2)               // 1024x512
#define WS_WCB    (WS_WE2 + 1024*512*2)               // 256x1024
#define WS_WD1    (WS_WCB + 256*1024*2)               // 512x256
#define WS_WD2    (WS_WD1 + 512*256*2)                // 256x512
#define WS_WK2    (WS_WD2 + 256*512*2)                // 512x512
#define WS_WSTK   (WS_WK2 + 512*512*2)                // 1024x256 [We1 ; Wk1[:,:256]]
#define WS_BSTK   (WS_WSTK + 1024*256*2)              // 1024 fp32 [b_e1 | 0]
#define WS_KPART  (WS_BSTK + 1024*4)                  // Bn fp32 (zeroed by cvt)
#define WS_BUFA   (WS_KPART + (size_t)Bn*4)           // Bn x 1024 bf16: [h1|kp1] -> q
#define WS_BUFB   (WS_BUFA + (size_t)Bn*1024*2)       // Bn x 1024 bf16: logits -> mask
#define WS_BUFC   (WS_BUFB + (size_t)Bn*1024*2)       // Bn x 512 bf16: xb -> hk1 -> hd1
#define WS_WE2T   (WS_BUFC + (size_t)Bn*512*2)        // 512x1024 bf16 (We2 transposed)
#define WS_WCOMB2 (WS_WE2T + 512*1024*2)              // 512x512 bf16 (Wk1b @ We2)
#define WS_BCONST (WS_WCOMB2 + 512*512*2)             // 512 fp32
// bf16 x (32768x256 = 16.8 MB) overlays bufC: written by cvt, read by E1
// (fusedA); fusedB overwrites the region with hk1 only AFTER E1 completes.
#define WS_BUFX   WS_BUFC

// cvt grid segmentation
#define CVT_BASE  2177
#define CVT_T     512
#define CVT_BC    128
#define CVT_KZ    32
#define CVT_X     4096
#define CVT_GRID  (CVT_BASE + CVT_T + CVT_BC + CVT_KZ + CVT_X)   // 6945

__device__ inline void async_copy16(const void* g, void* l) {
    __builtin_amdgcn_global_load_lds(
        (const __attribute__((address_space(1))) void*)g,
        (__attribute__((address_space(3))) void*)l, 16, 0, 0);
}

__device__ inline void cv4(bf16* d, float4 v) {
    union { short4 s; bf16 h[4]; } u;
    u.h[0] = __float2bfloat16(v.x); u.h[1] = __float2bfloat16(v.y);
    u.h[2] = __float2bfloat16(v.z); u.h[3] = __float2bfloat16(v.w);
    *(short4*)d = u.s;
}

// ---------------------------------------------------------------------------
// One-shot prep: all weight bf16 conversions, stacked [We1;Wk1a] + bias,
// We2 transpose, bconst = Wk1b . b_e2 + b_k1, kpart zeroing, x -> bf16.
// ---------------------------------------------------------------------------
__global__ __launch_bounds__(256) void cvt_kernel(
    const float* __restrict__ We1, const float* __restrict__ We2,
    const float* __restrict__ Wcb, const float* __restrict__ Wd1,
    const float* __restrict__ Wd2, const float* __restrict__ Wk1,
    const float* __restrict__ Wk2, const float* __restrict__ be1,
    const float* __restrict__ be2, const float* __restrict__ bk1,
    const float* __restrict__ x, char* __restrict__ ws)
{
    const int bx = blockIdx.x, tid = threadIdx.x;
    if (bx < CVT_BASE) {
        int id = bx * 256 + tid;
        const float* src; bf16* dst; int off;
        if      (id < 163840) { src = Wk1; dst = (bf16*)(ws + WS_WK1); off = id; }
        else if (id < 294912) { src = We2; dst = (bf16*)(ws + WS_WE2); off = id - 163840; }
        else if (id < 360448) { src = Wcb; dst = (bf16*)(ws + WS_WCB); off = id - 294912; }
        else if (id < 393216) { src = Wd1; dst = (bf16*)(ws + WS_WD1); off = id - 360448; }
        else if (id < 425984) { src = Wd2; dst = (bf16*)(ws + WS_WD2); off = id - 393216; }
        else if (id < 491520) { src = Wk2; dst = (bf16*)(ws + WS_WK2); off = id - 425984; }
        else if (id < 524288) { src = We1; dst = (bf16*)(ws + WS_WSTK); off = id - 491520; }
        else if (id < 557056) {           // Wk1[:, :256] -> wstk rows 512..1023
            int l = id - 524288; int r = l >> 6, c4 = (l & 63) * 4;
            float4 v = *(const float4*)(Wk1 + (size_t)r * 1280 + c4);
            cv4((bf16*)(ws + WS_WSTK) + 131072 + r * 256 + c4, v);
            return;
        } else {                           // bias_stk: [b_e1 | zeros], fp32
            int l = id - 557056;
            float4 v = (l < 128) ? *(const float4*)(be1 + l * 4)
                                 : make_float4(0.f, 0.f, 0.f, 0.f);
            *(float4*)((float*)(ws + WS_BSTK) + l * 4) = v;
            return;
        }
        float4 v = *(const float4*)(src + (size_t)off * 4);
        cv4(dst + (size_t)off * 4, v);
    } else if (bx < CVT_BASE + CVT_T) {
        int local = (bx - CVT_BASE) * 256 + tid;
        int n = local & 511;
        int k = (local >> 9) * 4;
        float4 v;
        v.x = We2[(size_t)(k + 0) * 512 + n];
        v.y = We2[(size_t)(k + 1) * 512 + n];
        v.z = We2[(size_t)(k + 2) * 512 + n];
        v.w = We2[(size_t)(k + 3) * 512 + n];
        cv4((bf16*)(ws + WS_WE2T) + (size_t)n * 1024 + k, v);
    } else if (bx < CVT_BASE + CVT_T + CVT_BC) {
        int r = (bx - CVT_BASE - CVT_T) * 4 + (tid >> 6);
        int lane = tid & 63;
        const float* wr = Wk1 + (size_t)r * 1280 + 256;
        float s = 0.f;
#pragma unroll
        for (int t = 0; t < 16; t++) {
            int j = lane + t * 64;
            s = fmaf(wr[j], be2[j], s);
        }
#pragma unroll
        for (int off = 32; off > 0; off >>= 1) s += __shfl_down(s, off);
        if (lane == 0) ((float*)(ws + WS_BCONST))[r] = s + bk1[r];
    } else if (bx < CVT_BASE + CVT_T + CVT_BC + CVT_KZ) {
        int idx = ((bx - CVT_BASE - CVT_T - CVT_BC) * 256 + tid) * 4;
        *(float4*)((float*)(ws + WS_KPART) + idx) = make_float4(0.f, 0.f, 0.f, 0.f);
    } else {
        // x (32768x256 fp32) -> bf16 bufX; 8 elems/thread, 16B stores
        int id = (bx - CVT_BASE - CVT_T - CVT_BC - CVT_KZ) * 256 + tid;
        const float* src = x + (size_t)id * 8;
        float4 v0 = *(const float4*)src;
        float4 v1 = *(const float4*)(src + 4);
        union { frag8 s; bf16 h[8]; } u;
        u.h[0] = __float2bfloat16(v0.x); u.h[1] = __float2bfloat16(v0.y);
        u.h[2] = __float2bfloat16(v0.z); u.h[3] = __float2bfloat16(v0.w);
        u.h[4] = __float2bfloat16(v1.x); u.h[5] = __float2bfloat16(v1.y);
        u.h[6] = __float2bfloat16(v1.z); u.h[7] = __float2bfloat16(v1.w);
        *(frag8*)((bf16*)(ws + WS_BUFX) + (size_t)id * 8) = u.s;
    }
}

// ---------------------------------------------------------------------------
// bf16 MFMA GEMM body: 256x256 block tile, BK=64, 8 waves (4Mx2N, 512 thr),
// wave = 64x128 (4x8 frags, acc 128 VGPR). Doubling BOTH tile dims halves
// total staged bytes (A: xN/256 re-reads, B: xM/256) vs 128^2 -> the multi-
// GEMM staging traffic drops 1877->~940 MB, which is the measured bottleneck
// (fusedB sustains ~8.4 TB/s staging at 128^2 = L2/L3 ceiling).
// LDS 64 KB (A 32K + B 32K), 1 block/CU (launch_bounds(512,2) -> <=256 VGPR).
// XOR-swizzled staging via global_load_lds.
// OMODE: 0 = bf16 C (coalesced via two 128-row LDS store-stage halves);
//        1 = fp32 C; 2 = kdot epilogue (atomicAdd).
// relu_ncols (runtime): relu applied iff global col < relu_ncols.
// ACCIN: epilogue adds bf16 accin[row*ldacc + col] before relu.
// ---------------------------------------------------------------------------
template<int OMODE, int BIAS, int INVK, int ACCIN>
__device__ __forceinline__ void gemm_body256(
    char* smem, int m0, int n0,
    const bf16* __restrict__ A, const u16* __restrict__ accin,
    const bf16* __restrict__ W, const float* __restrict__ bias,
    const float* __restrict__ kv, void* __restrict__ Cp,
    int K, int lda, int ldw, int ldc, int ldacc, int relu_ncols)
{
    bf16* sA = (bf16*)smem;               // 256 x 64 = 32 KB
    bf16* sB = (bf16*)(smem + 32768);     // 256 x 64 = 32 KB

    const int tid = threadIdx.x;
    const int wv = tid >> 6, ln = tid & 63;
    const int wr = wv >> 1, wc = wv & 1;     // 4 M-waves x 2 N-waves
    const int lm = ln & 15, q = ln >> 4;

    f32x4 acc[4][8];
#pragma unroll
    for (int i = 0; i < 4; i++)
#pragma unroll
        for (int j = 0; j < 8; j++)
            acc[i][j] = (f32x4){0.f, 0.f, 0.f, 0.f};

    for (int k0 = 0; k0 < K; k0 += 64) {
        // ---- stage A (256 rows x 64 k): 4 gload_lds/thread ----
#pragma unroll
        for (int i = 0; i < 4; i++) {
            int c = i * 512 + tid;            // 0..2047
            int row = c >> 3;                 // 0..255
            int g = (c & 7) ^ (row & 7);
            async_copy16(A + (size_t)(m0 + row) * lda + k0 + g * 8, &sA[c * 8]);
        }
        // ---- stage W tile (256 rows x 64 k): 4 gload_lds/thread ----
#pragma unroll
        for (int i = 0; i < 4; i++) {
            int c = i * 512 + tid;
            int row = c >> 3;
            int g = (c & 7) ^ (row & 7);
            async_copy16(W + (size_t)(n0 + row) * ldw + k0 + g * 8, &sB[c * 8]);
        }
        __syncthreads();

#pragma unroll
        for (int kk = 0; kk < 2; kk++) {
            frag8 af[4], bfr[8];
#pragma unroll
            for (int t = 0; t < 4; t++) {
                int r = wr * 64 + t * 16 + lm;
                af[t] = *(const frag8*)&sA[r * 64 + (((kk * 4 + q) ^ (r & 7)) * 8)];
            }
#pragma unroll
            for (int t = 0; t < 8; t++) {
                int n = wc * 128 + t * 16 + lm;
                bfr[t] = *(const frag8*)&sB[n * 64 + (((kk * 4 + q) ^ (n & 7)) * 8)];
            }
#pragma unroll
            for (int mt = 0; mt < 4; mt++)
#pragma unroll
                for (int nt = 0; nt < 8; nt++)
                    acc[mt][nt] = __builtin_amdgcn_mfma_f32_16x16x32_bf16(
                        af[mt], bfr[nt], acc[mt][nt], 0, 0, 0);
        }
        __syncthreads();
    }

    // ---- epilogue (C frag layout: col=lane&15, row=(lane>>4)*4+reg) ----
    if (OMODE == 2) {
        float* kpart = (float*)Cp;
#pragma unroll
        for (int mt = 0; mt < 4; mt++) {
#pragma unroll
            for (int r = 0; r < 4; r++) {
                int row = m0 + wr * 64 + mt * 16 + q * 4 + r;
                float s = 0.f;
#pragma unroll
                for (int nt = 0; nt < 8; nt++) {
                    int col = n0 + wc * 128 + nt * 16 + lm;
                    float v = acc[mt][nt][r] + bias[col];
                    v = fmaxf(v, 0.f);
                    s = fmaf(v, kv[col], s);
                }
#pragma unroll
                for (int off = 8; off > 0; off >>= 1) s += __shfl_down(s, off);
                if (lm == 0) atomicAdd(&kpart[row], s);
            }
        }
    } else if (OMODE == 1) {
#pragma unroll
        for (int mt = 0; mt < 4; mt++) {
#pragma unroll
            for (int r = 0; r < 4; r++) {
                int row = m0 + wr * 64 + mt * 16 + q * 4 + r;
#pragma unroll
                for (int nt = 0; nt < 8; nt++) {
                    int col = n0 + wc * 128 + nt * 16 + lm;
                    float v = acc[mt][nt][r];
                    if (BIAS) v += bias[col];
                    if (col < relu_ncols) v = fmaxf(v, 0.f);
                    ((float*)Cp)[(size_t)row * ldc + col] = v;
                }
            }
        }
    } else {
        // bf16 C via LDS store-stage, two 128-row halves (64 KB overlay)
        u16* st = (u16*)smem;   // 128 x 256 bf16 = 64 KB
        u16* Cb = (u16*)Cp;
#pragma unroll
        for (int half = 0; half < 2; half++) {
            if ((wr >> 1) == half) {   // waves owning rows of this half
#pragma unroll
                for (int mt = 0; mt < 4; mt++) {
#pragma unroll
                    for (int r = 0; r < 4; r++) {
                        int rl = (wr & 1) * 64 + mt * 16 + q * 4 + r;   // 0..127
                        int rg = m0 + half * 128 + rl;
                        float scale = 1.0f;
                        if (INVK) scale = 1.0f / kv[rg];
#pragma unroll
                        for (int nt = 0; nt < 8; nt++) {
                            int cl = wc * 128 + nt * 16 + lm;
                            int cg = n0 + cl;
                            float v = acc[mt][nt][r];
                            if (BIAS) v += bias[cg];
                            if (ACCIN) {
                                u16 raw = accin[(size_t)rg * ldacc + cg];
                                union { u16 u; bf16 h; } cu; cu.u = raw;
                                v += __bfloat162float(cu.h);
                            }
                            if (INVK) v *= scale;
                            if (cg < relu_ncols) v = fmaxf(v, 0.f);
                            union { u16 u; bf16 h; } ou; ou.h = __float2bfloat16(v);
                            st[rl * 256 + cl] = ou.u;
                        }
                    }
                }
            }
            __syncthreads();
            // 512 threads copy 128x256 u16 = 4096 uint4; 8 per thread
#pragma unroll
            for (int c = 0; c < 8; c++) {
                int idx = tid + c * 512;              // 0..4095
                int rl = idx >> 5, cl = (idx & 31) * 8;
                *(uint4*)(Cb + (size_t)(m0 + half * 128 + rl) * ldc + n0 + cl)
                    = ((const uint4*)st)[idx];
            }
            __syncthreads();
        }
    }
}

// Standalone GEMM wrapper: 1-D grid (multiple of 8), XCD-chunked swizzle,
// NCH = number of 256-col N-chunks (compile-time for cheap div/mod).
template<int OMODE, int BIAS, int INVK, int ACCIN, int NCH>
__global__ __launch_bounds__(512, 2) void mgemm(
    const bf16* __restrict__ Ap, const u16* __restrict__ accin,
    const bf16* __restrict__ W, const float* __restrict__ bias,
    const float* __restrict__ kv, void* __restrict__ Cp,
    int K, int lda, int ldw, int ldc, int ldacc, int relu_ncols)
{
    __shared__ __align__(16) char smem[65536];
    const int bid = blockIdx.x;
    const int cpx = gridDim.x >> 3;
    const int wg = (bid & 7) * cpx + (bid >> 3);
    const int nc = wg % NCH, mc = wg / NCH;
    gemm_body256<OMODE, BIAS, INVK, ACCIN>(
        smem, mc * 256, nc * 256,
        Ap, accin, W, bias, kv, Cp, K, lda, ldw, ldc, ldacc, relu_ncols);
}

// fusedA: bid<4 -> Wcomb2 = Wk1b @ We2 (M=512 N=512 K=1024), placed FIRST so
// it hides under E1's 512 blocks. bid>=4 -> E1||K1a over bf16 x (K=256).
__global__ __launch_bounds__(512, 2) void fusedA_kernel(
    const bf16* __restrict__ xb, const bf16* __restrict__ wstk,
    const float* __restrict__ bstk, bf16* __restrict__ bufA,
    const bf16* __restrict__ wk1b, const bf16* __restrict__ we2t,
    bf16* __restrict__ wcomb2)
{
    __shared__ __align__(16) char smem[65536];
    const int bid = blockIdx.x;
    if (bid < 4) {
        gemm_body256<0, 0, 0, 0>(smem, (bid >> 1) * 256, (bid & 1) * 256,
            wk1b, nullptr, we2t, nullptr, nullptr, wcomb2, 1024, 1280, 1024, 512, 0, 0);
    } else {
        const int b = bid - 4;                        // [0, 512)
        const int wg = (b & 7) * 64 + (b >> 3);
        const int mc = wg >> 2, nc = wg & 3;          // 128 M-chunks x 4 N-chunks
        gemm_body256<0, 1, 0, 0>(smem, mc * 256, nc * 256,
            xb, nullptr, wstk, bstk, nullptr, bufA, 256, 256, 256, 1024, 0, 512);
    }
}

// fusedB: combined chunk id c in [0,6): c<4 -> E2 n-chunk c; c>=4 -> K1b'
// n-chunk c-4. Both depend only on bufA; grid 768 (128 mc x 6).
__global__ __launch_bounds__(512, 2) void fusedB_kernel(
    const bf16* __restrict__ bufA, const bf16* __restrict__ we2w,
    const float* __restrict__ be2, bf16* __restrict__ bufB,
    const bf16* __restrict__ wcomb2, const float* __restrict__ bconst,
    bf16* __restrict__ bufC)
{
    __shared__ __align__(16) char smem[65536];
    const int bid = blockIdx.x;                       // [0, 768)
    const int wg = (bid & 7) * 96 + (bid >> 3);
    const int nc = wg % 6, mc = wg / 6;
    if (nc < 4) {
        gemm_body256<0, 1, 0, 0>(smem, mc * 256, nc * 256,
            bufA, nullptr, we2w, be2, nullptr, bufB, 512, 1024, 512, 1024, 0, 0);
    } else {
        gemm_body256<0, 1, 0, 1>(smem, mc * 256, (nc - 4) * 256,
            bufA, (const u16*)bufA + 512, wcomb2, bconst, nullptr, bufC,
            512, 1024, 512, 512, 1024, 1 << 30);
    }
}

// ---------------------------------------------------------------------------
// khot + kfinal fused: wave-per-row (R1/R7-measured version). Computes k from
// kpart, writes kout/scl, then top-m mask on bf16 keys (2x8-bit radix,
// per-wave LDS histogram split into 8 per-lane-group sub-histograms with a
// 264-stride bank skew). Writes fp32 mask (d_out) + bf16 mask (in place).
// ---------------------------------------------------------------------------
#define KH_GS 264   // sub-histogram stride (256 + 8 -> groups offset by 8 banks)

__device__ inline void suffix_pick(const unsigned* h, int lane, unsigned target,
                                   unsigned& bucket, unsigned& rem)
{
    uint4 hv = make_uint4(0u, 0u, 0u, 0u);
#pragma unroll
    for (int g = 0; g < 8; g++) {
        uint4 t = *(const uint4*)(h + g * KH_GS + lane * 4);
        hv.x += t.x; hv.y += t.y; hv.z += t.z; hv.w += t.w;
    }
    unsigned local = hv.x + hv.y + hv.z + hv.w;
    unsigned incl = local;
#pragma unroll
    for (int off = 1; off < 64; off <<= 1) {
        unsigned t = __shfl_down(incl, off);
        if (lane + off < 64) incl += t;
    }
    unsigned higher = incl - local;
    unsigned s3 = higher + hv.w;
    unsigned s2 = s3 + hv.z;
    unsigned s1 = s2 + hv.y;
    unsigned s0 = s1 + hv.x;
    unsigned suf[5] = {s0, s1, s2, s3, higher};
    int bj = -1; unsigned rm = 0;
#pragma unroll
    for (int j = 0; j < 4; j++)
        if (suf[j] >= target && suf[j + 1] < target) { bj = j; rm = target - suf[j + 1]; }
    unsigned long long mk = __ballot(bj >= 0);
    int src = (int)__ffsll((unsigned long long)mk) - 1;
    bucket = __shfl((unsigned)(lane * 4 + bj), src);
    rem    = __shfl(rm, src);
}

__device__ inline void hist_zero(unsigned* h, int lane) {
    uint4* h4 = (uint4*)h;                 // 8*264 u32 = 528 uint4
#pragma unroll
    for (int i = 0; i < 8; i++) h4[lane + i * 64] = make_uint4(0u, 0u, 0u, 0u);
    if (lane < 16) h4[512 + lane] = make_uint4(0u, 0u, 0u, 0u);
}

__global__ __launch_bounds__(256) void khot_kernel(
    u16* __restrict__ lb, const float* __restrict__ kpart,
    const float* __restrict__ b3, const float* __restrict__ kscale,
    float* __restrict__ mf, float* __restrict__ kout, float* __restrict__ scl)
{
    __shared__ unsigned hist[4][8 * KH_GS];   // 4 waves x 8.25 KB = 33 KB
    const int w = threadIdx.x >> 6, lane = threadIdx.x & 63;
    const int row = blockIdx.x * 4 + w;
    u16* rp = lb + (size_t)row * QDIM;
    float* mfp = mf + (size_t)row * QDIM;

    float z = kpart[row] + b3[0];
    float kk = 1024.0f / (1.0f + expf(-z));
    float sc = 1.0f / (1.0f + expf(-kscale[0]));
    float kvv = fminf(fmaxf(kk * sc * 2.0f, 1.0f), 1024.0f);
    if (lane == 0) kout[row] = kvv;
    if (row == 0 && lane == 0) scl[0] = 0.0f;

    u16x8 v0 = *(const u16x8*)(rp + lane * 8);
    u16x8 v1 = *(const u16x8*)(rp + 512 + lane * 8);
    unsigned key[2][8];
#pragma unroll
    for (int j = 0; j < 8; j++) {
        unsigned a = v0[j], b = v1[j];
        key[0][j] = (a & 0x8000u) ? (~a & 0xffffu) : (a | 0x8000u);
        key[1][j] = (b & 0x8000u) ? (~b & 0xffffu) : (b | 0x8000u);
    }
    int mi = (int)ceilf(kvv);
    mi = mi < 1 ? 1 : (mi > QDIM ? QDIM : mi);
    const unsigned m = (unsigned)mi;
    unsigned* h = hist[w];
    unsigned* hg = h + (lane >> 3) * KH_GS;   // this lane's sub-histogram

    hist_zero(h, lane);
    __threadfence_block();
#pragma unroll
    for (int c = 0; c < 2; c++)
#pragma unroll
        for (int j = 0; j < 8; j++)
            atomicAdd(&hg[key[c][j] >> 8], 1u);
    __threadfence_block();
    unsigned hi, rem1;
    suffix_pick(h, lane, m, hi, rem1);

    hist_zero(h, lane);
    __threadfence_block();
#pragma unroll
    for (int c = 0; c < 2; c++)
#pragma unroll
        for (int j = 0; j < 8; j++)
            if ((key[c][j] >> 8) == hi) atomicAdd(&hg[key[c][j] & 255u], 1u);
    __threadfence_block();
    unsigned lo, need;
    suffix_pick(h, lane, rem1, lo, need);

    const unsigned um = (hi << 8) | lo;

    unsigned cnt0 = 0, cnt1 = 0;
#pragma unroll
    for (int j = 0; j < 8; j++) { cnt0 += (key[0][j] == um); cnt1 += (key[1][j] == um); }
    unsigned pack = cnt0 | (cnt1 << 16);
    unsigned incl = pack;
#pragma unroll
    for (int off = 1; off < 64; off <<= 1) {
        unsigned t = __shfl_up(incl, off);
        if (lane >= off) incl += t;
    }
    unsigned excl = incl - pack;
    unsigned tot0 = __shfl(incl, 63) & 0xffffu;
    unsigned r0 = excl & 0xffffu;
    unsigned r1 = tot0 + (excl >> 16);

    float of[2][8];
    u16x8 mb0, mb1;
#pragma unroll
    for (int j = 0; j < 8; j++) {
        unsigned kv_ = key[0][j];
        bool s;
        if (kv_ > um) s = true;
        else if (kv_ == um) { s = (r0 < need); r0++; }
        else s = false;
        of[0][j] = s ? 1.0f : 0.0f;
        mb0[j] = s ? (u16)0x3F80 : (u16)0;
    }
#pragma unroll
    for (int j = 0; j < 8; j++) {
        unsigned kv_ = key[1][j];
        bool s;
        if (kv_ > um) s = true;
        else if (kv_ == um) { s = (r1 < need); r1++; }
        else s = false;
        of[1][j] = s ? 1.0f : 0.0f;
        mb1[j] = s ? (u16)0x3F80 : (u16)0;
    }
    *(float4*)(mfp + lane * 8)           = make_float4(of[0][0], of[0][1], of[0][2], of[0][3]);
    *(float4*)(mfp + lane * 8 + 4)       = make_float4(of[0][4], of[0][5], of[0][6], of[0][7]);
    *(float4*)(mfp + 512 + lane * 8)     = make_float4(of[1][0], of[1][1], of[1][2], of[1][3]);
    *(float4*)(mfp + 512 + lane * 8 + 4) = make_float4(of[1][4], of[1][5], of[1][6], of[1][7]);
    *(u16x8*)(rp + lane * 8)       = mb0;
    *(u16x8*)(rp + 512 + lane * 8) = mb1;
}

// ---------------------------------------------------------------------------
extern "C" void kernel_launch(void* const* d_in, const int* in_sizes, int n_in,
                              void* d_out, int out_size, void* d_ws, size_t ws_size,
                              hipStream_t stream) {
    const float* x     = (const float*)d_in[0];
    const float* W_e1  = (const float*)d_in[1];
    const float* b_e1  = (const float*)d_in[2];
    const float* W_e2  = (const float*)d_in[3];
    const float* b_e2  = (const float*)d_in[4];
    const float* W_cb  = (const float*)d_in[5];
    const float* W_d1  = (const float*)d_in[6];
    const float* b_d1  = (const float*)d_in[7];
    const float* W_d2  = (const float*)d_in[8];
    const float* b_d2  = (const float*)d_in[9];
    const float* W_k1  = (const float*)d_in[10];
    const float* b_k1  = (const float*)d_in[11];
    const float* W_k2  = (const float*)d_in[12];
    const float* b_k2  = (const float*)d_in[13];
    const float* W_k3  = (const float*)d_in[14];
    const float* b_k3  = (const float*)d_in[15];
    const float* k_scl = (const float*)d_in[16];

    float* out   = (float*)d_out;
    float* recon = out;
    float* maskf = out + OUT_KHOT_OFF;
    float* scl   = out + OUT_SCALAR_OFF;
    float* kout  = out + OUT_K_OFF;

    char* ws = (char*)d_ws;
    bf16* wb_k1  = (bf16*)(ws + WS_WK1);
    bf16* wb_e2  = (bf16*)(ws + WS_WE2);
    bf16* wb_cb  = (bf16*)(ws + WS_WCB);
    bf16* wb_d1  = (bf16*)(ws + WS_WD1);
    bf16* wb_d2  = (bf16*)(ws + WS_WD2);
    bf16* wb_k2  = (bf16*)(ws + WS_WK2);
    bf16* wstk   = (bf16*)(ws + WS_WSTK);
    float* bstk  = (float*)(ws + WS_BSTK);
    float* kpart = (float*)(ws + WS_KPART);
    bf16* bufA   = (bf16*)(ws + WS_BUFA);
    bf16* bufB   = (bf16*)(ws + WS_BUFB);
    bf16* bufC   = (bf16*)(ws + WS_BUFC);
    bf16* bufX   = (bf16*)(ws + WS_BUFX);
    bf16* we2t   = (bf16*)(ws + WS_WE2T);
    bf16* wcomb2 = (bf16*)(ws + WS_WCOMB2);
    float* bconst = (float*)(ws + WS_BCONST);

    const dim3 blk(256);
    const dim3 blk512(512);
    const int FULL = 1 << 30;

    // prep: conversions (incl. x->bf16) + stacked W/b + We2T + bconst + kpart
    cvt_kernel<<<dim3(CVT_GRID), blk, 0, stream>>>(
        W_e1, W_e2, W_cb, W_d1, W_d2, W_k1, W_k2, b_e1, b_e2, b_k1, x, ws);

    // Wcomb2 (4 blocks, overlapped under E1) + E1||K1a (512 blocks, swizzled)
    fusedA_kernel<<<dim3(516), blk512, 0, stream>>>(
        bufX, wstk, bstk, bufA, wb_k1 + 256, we2t, wcomb2);

    // E2 + K1b' merged (768 blocks)
    fusedB_kernel<<<dim3(768), blk512, 0, stream>>>(
        bufA, wb_e2, b_e2, bufB, wcomb2, bconst, bufC);

    // K2+kdot: kpart[row] += relu(hk1 @ Wk2^T + b_k2) . w3   (NCH=2)
    mgemm<2, 1, 0, 0, 2><<<dim3(256), blk512, 0, stream>>>(
        bufC, nullptr, wb_k2, b_k2, W_k3, kpart, 512, 512, 512, 512, 0, FULL);

    // khot (+kfinal): logits -> fp32 mask (d_out) + bf16 mask; k -> kout/scl
    khot_kernel<<<dim3(Bn / 4), blk, 0, stream>>>(
        (u16*)bufB, kpart, b_k3, k_scl, maskf, kout, scl);

    // CB: q = (mask/k) @ Wcb^T -> bufA (ldc 256; [h1|kp1] dead)  (NCH=1)
    mgemm<0, 0, 1, 0, 1><<<dim3(128), blk512, 0, stream>>>(
        bufB, nullptr, wb_cb, nullptr, kout, bufA, 1024, 1024, 1024, 256, 0, 0);

    // D1: hd1 = relu(q @ Wd1^T + b_d1) -> bufC   (NCH=2)
    mgemm<0, 1, 0, 0, 2><<<dim3(256), blk512, 0, stream>>>(
        bufA, nullptr, wb_d1, b_d1, nullptr, bufC, 256, 256, 256, 512, 0, FULL);

    // D2: recon = hd1 @ Wd2^T + b_d2 -> d_out (fp32)   (NCH=1)
    mgemm<1, 1, 0, 0, 1><<<dim3(128), blk512, 0, stream>>>(
        bufC, nullptr, wb_d2, b_d2, nullptr, recon, 512, 512, 512, 256, 0, 0);
}

// Round 10
// 468.433 us; speedup vs baseline: 1.2162x; 1.2162x over previous
//
#include <hip/hip_runtime.h>
#include <hip/hip_bf16.h>
#include <math.h>

typedef __hip_bfloat16 bf16;
typedef unsigned short u16;
using frag8 = __attribute__((ext_vector_type(8))) short;   // 8 bf16 = 4 VGPRs
using f32x4 = __attribute__((ext_vector_type(4))) float;   // MFMA accumulator
using u16x8 = __attribute__((ext_vector_type(8))) unsigned short;

// Problem constants
#define Bn      32768
#define IN_DIM  256
#define N_HDIM  512
#define QDIM    1024
#define N_EMBD  256

// Output layout (float32): recon [B*256] | khot [B*1024] | scalar [1] | k [B]
#define OUT_KHOT_OFF   ((size_t)Bn * IN_DIM)
#define OUT_SCALAR_OFF (OUT_KHOT_OFF + (size_t)Bn * QDIM)
#define OUT_K_OFF      (OUT_SCALAR_OFF + 1)

// Workspace layout (bytes)
#define WS_WK1    0                                   // 512x1280 bf16 (full)
#define WS_WE2    (WS_WK1 + 512*1280*2)               // 1024x512
#define WS_WCB    (WS_WE2 + 1024*512*2)               // 256x1024
#define WS_WD1    (WS_WCB + 256*1024*2)               // 512x256
#define WS_WD2    (WS_WD1 + 512*256*2)                // 256x512
#define WS_WK2    (WS_WD2 + 256*512*2)                // 512x512
#define WS_WSTK   (WS_WK2 + 512*512*2)                // 1024x256 [We1 ; Wk1[:,:256]]
#define WS_BSTK   (WS_WSTK + 1024*256*2)              // 1024 fp32 [b_e1 | 0]
#define WS_KPART  (WS_BSTK + 1024*4)                  // Bn fp32 (zeroed by cvt)
#define WS_BUFA   (WS_KPART + (size_t)Bn*4)           // Bn x 1024 bf16: [h1|kp1] -> q
#define WS_BUFB   (WS_BUFA + (size_t)Bn*1024*2)       // Bn x 1024 bf16: logits -> mask
#define WS_BUFC   (WS_BUFB + (size_t)Bn*1024*2)       // Bn x 512 bf16: xb -> hk1 -> hd1
#define WS_WE2T   (WS_BUFC + (size_t)Bn*512*2)        // 512x1024 bf16 (We2 transposed)
#define WS_WCOMB2 (WS_WE2T + 512*1024*2)              // 512x512 bf16 (Wk1b @ We2)
#define WS_BCONST (WS_WCOMB2 + 512*512*2)             // 512 fp32
// bf16 x (32768x256 = 16.8 MB) overlays bufC: written by cvt, read by E1
// (fusedA); fusedB overwrites the region with hk1 only AFTER E1 completes.
#define WS_BUFX   WS_BUFC

// cvt grid segmentation
#define CVT_BASE  2177
#define CVT_T     512
#define CVT_BC    128
#define CVT_KZ    32
#define CVT_X     4096
#define CVT_GRID  (CVT_BASE + CVT_T + CVT_BC + CVT_KZ + CVT_X)   // 6945

__device__ inline void async_copy16(const void* g, void* l) {
    __builtin_amdgcn_global_load_lds(
        (const __attribute__((address_space(1))) void*)g,
        (__attribute__((address_space(3))) void*)l, 16, 0, 0);
}

__device__ inline void cv4(bf16* d, float4 v) {
    union { short4 s; bf16 h[4]; } u;
    u.h[0] = __float2bfloat16(v.x); u.h[1] = __float2bfloat16(v.y);
    u.h[2] = __float2bfloat16(v.z); u.h[3] = __float2bfloat16(v.w);
    *(short4*)d = u.s;
}

// ---------------------------------------------------------------------------
// One-shot prep: all weight bf16 conversions, stacked [We1;Wk1a] + bias,
// We2 transpose, bconst = Wk1b . b_e2 + b_k1, kpart zeroing, x -> bf16.
// ---------------------------------------------------------------------------
__global__ __launch_bounds__(256) void cvt_kernel(
    const float* __restrict__ We1, const float* __restrict__ We2,
    const float* __restrict__ Wcb, const float* __restrict__ Wd1,
    const float* __restrict__ Wd2, const float* __restrict__ Wk1,
    const float* __restrict__ Wk2, const float* __restrict__ be1,
    const float* __restrict__ be2, const float* __restrict__ bk1,
    const float* __restrict__ x, char* __restrict__ ws)
{
    const int bx = blockIdx.x, tid = threadIdx.x;
    if (bx < CVT_BASE) {
        int id = bx * 256 + tid;
        const float* src; bf16* dst; int off;
        if      (id < 163840) { src = Wk1; dst = (bf16*)(ws + WS_WK1); off = id; }
        else if (id < 294912) { src = We2; dst = (bf16*)(ws + WS_WE2); off = id - 163840; }
        else if (id < 360448) { src = Wcb; dst = (bf16*)(ws + WS_WCB); off = id - 294912; }
        else if (id < 393216) { src = Wd1; dst = (bf16*)(ws + WS_WD1); off = id - 360448; }
        else if (id < 425984) { src = Wd2; dst = (bf16*)(ws + WS_WD2); off = id - 393216; }
        else if (id < 491520) { src = Wk2; dst = (bf16*)(ws + WS_WK2); off = id - 425984; }
        else if (id < 524288) { src = We1; dst = (bf16*)(ws + WS_WSTK); off = id - 491520; }
        else if (id < 557056) {           // Wk1[:, :256] -> wstk rows 512..1023
            int l = id - 524288; int r = l >> 6, c4 = (l & 63) * 4;
            float4 v = *(const float4*)(Wk1 + (size_t)r * 1280 + c4);
            cv4((bf16*)(ws + WS_WSTK) + 131072 + r * 256 + c4, v);
            return;
        } else {                           // bias_stk: [b_e1 | zeros], fp32
            int l = id - 557056;
            float4 v = (l < 128) ? *(const float4*)(be1 + l * 4)
                                 : make_float4(0.f, 0.f, 0.f, 0.f);
            *(float4*)((float*)(ws + WS_BSTK) + l * 4) = v;
            return;
        }
        float4 v = *(const float4*)(src + (size_t)off * 4);
        cv4(dst + (size_t)off * 4, v);
    } else if (bx < CVT_BASE + CVT_T) {
        int local = (bx - CVT_BASE) * 256 + tid;
        int n = local & 511;
        int k = (local >> 9) * 4;
        float4 v;
        v.x = We2[(size_t)(k + 0) * 512 + n];
        v.y = We2[(size_t)(k + 1) * 512 + n];
        v.z = We2[(size_t)(k + 2) * 512 + n];
        v.w = We2[(size_t)(k + 3) * 512 + n];
        cv4((bf16*)(ws + WS_WE2T) + (size_t)n * 1024 + k, v);
    } else if (bx < CVT_BASE + CVT_T + CVT_BC) {
        int r = (bx - CVT_BASE - CVT_T) * 4 + (tid >> 6);
        int lane = tid & 63;
        const float* wr = Wk1 + (size_t)r * 1280 + 256;
        float s = 0.f;
#pragma unroll
        for (int t = 0; t < 16; t++) {
            int j = lane + t * 64;
            s = fmaf(wr[j], be2[j], s);
        }
#pragma unroll
        for (int off = 32; off > 0; off >>= 1) s += __shfl_down(s, off);
        if (lane == 0) ((float*)(ws + WS_BCONST))[r] = s + bk1[r];
    } else if (bx < CVT_BASE + CVT_T + CVT_BC + CVT_KZ) {
        int idx = ((bx - CVT_BASE - CVT_T - CVT_BC) * 256 + tid) * 4;
        *(float4*)((float*)(ws + WS_KPART) + idx) = make_float4(0.f, 0.f, 0.f, 0.f);
    } else {
        // x (32768x256 fp32) -> bf16 bufX; 8 elems/thread, 16B stores
        int id = (bx - CVT_BASE - CVT_T - CVT_BC - CVT_KZ) * 256 + tid;
        const float* src = x + (size_t)id * 8;
        float4 v0 = *(const float4*)src;
        float4 v1 = *(const float4*)(src + 4);
        union { frag8 s; bf16 h[8]; } u;
        u.h[0] = __float2bfloat16(v0.x); u.h[1] = __float2bfloat16(v0.y);
        u.h[2] = __float2bfloat16(v0.z); u.h[3] = __float2bfloat16(v0.w);
        u.h[4] = __float2bfloat16(v1.x); u.h[5] = __float2bfloat16(v1.y);
        u.h[6] = __float2bfloat16(v1.z); u.h[7] = __float2bfloat16(v1.w);
        *(frag8*)((bf16*)(ws + WS_BUFX) + (size_t)id * 8) = u.s;
    }
}

// ---------------------------------------------------------------------------
// 256x256 PIPELINED GEMM body: BK=64, 8 waves (4Mx2N, 512 thr), wave 64x128.
// LDS 128 KB = DOUBLE-buffered {A 32K + B 32K} x 2. Counted-vmcnt pipeline:
// loads for K-tile t+1 stay in flight across tile t's barriers (vmcnt(8),
// never 0 in-loop) -> within-wave stage/compute overlap at 1 block/CU, which
// R9's counters showed is the missing latency hiding (MfmaUtil 16%,
// VALUBusy 12%, occupancy 17%, HBM 16% => latency-bound 2-barrier drain).
// Raw s_barrier (no implicit vmcnt(0) drain) + sched_barrier(0) pins.
// setprio(1) around the MFMA cluster (T5; pays on phase-split 256²).
// Compute/epilogue code identical to the R9-refchecked version.
// ---------------------------------------------------------------------------
template<int OMODE, int BIAS, int INVK, int ACCIN>
__device__ __forceinline__ void gemm_body256(
    char* smem, int m0, int n0,
    const bf16* __restrict__ A, const u16* __restrict__ accin,
    const bf16* __restrict__ W, const float* __restrict__ bias,
    const float* __restrict__ kv, void* __restrict__ Cp,
    int K, int lda, int ldw, int ldc, int ldacc, int relu_ncols)
{
    const int tid = threadIdx.x;
    const int wv = tid >> 6, ln = tid & 63;
    const int wr = wv >> 1, wc = wv & 1;     // 4 M-waves x 2 N-waves
    const int lm = ln & 15, q = ln >> 4;

    f32x4 acc[4][8];
#pragma unroll
    for (int i = 0; i < 4; i++)
#pragma unroll
        for (int j = 0; j < 8; j++)
            acc[i][j] = (f32x4){0.f, 0.f, 0.f, 0.f};

    const int NT = K >> 6;

    auto stage = [&](int t, int b) {
        bf16* sA = (bf16*)(smem + b * 65536);
        bf16* sB = (bf16*)(smem + b * 65536 + 32768);
        const int k0 = t * 64;
#pragma unroll
        for (int i = 0; i < 4; i++) {
            int c = i * 512 + tid;            // 0..2047
            int row = c >> 3;                 // 0..255
            int g = (c & 7) ^ (row & 7);
            async_copy16(A + (size_t)(m0 + row) * lda + k0 + g * 8, &sA[c * 8]);
        }
#pragma unroll
        for (int i = 0; i < 4; i++) {
            int c = i * 512 + tid;
            int row = c >> 3;
            int g = (c & 7) ^ (row & 7);
            async_copy16(W + (size_t)(n0 + row) * ldw + k0 + g * 8, &sB[c * 8]);
        }
    };

    stage(0, 0);
    if (NT > 1) stage(1, 1);
    int cur = 0;
    for (int t = 0; t < NT; t++) {
        // wait for MY tile-t loads (8 oldest); tile-(t+1)'s 8 stay in flight
        if (t + 1 < NT) { asm volatile("s_waitcnt vmcnt(8)" ::: "memory"); }
        else            { asm volatile("s_waitcnt vmcnt(0)" ::: "memory"); }
        __builtin_amdgcn_s_barrier();          // all waves' tile-t data in LDS
        __builtin_amdgcn_sched_barrier(0);

        bf16* sA = (bf16*)(smem + cur * 65536);
        bf16* sB = (bf16*)(smem + cur * 65536 + 32768);
#pragma unroll
        for (int kk = 0; kk < 2; kk++) {
            frag8 af[4], bfr[8];
#pragma unroll
            for (int tt = 0; tt < 4; tt++) {
                int r = wr * 64 + tt * 16 + lm;
                af[tt] = *(const frag8*)&sA[r * 64 + (((kk * 4 + q) ^ (r & 7)) * 8)];
            }
#pragma unroll
            for (int tt = 0; tt < 8; tt++) {
                int n = wc * 128 + tt * 16 + lm;
                bfr[tt] = *(const frag8*)&sB[n * 64 + (((kk * 4 + q) ^ (n & 7)) * 8)];
            }
            __builtin_amdgcn_s_setprio(1);
#pragma unroll
            for (int mt = 0; mt < 4; mt++)
#pragma unroll
                for (int nt = 0; nt < 8; nt++)
                    acc[mt][nt] = __builtin_amdgcn_mfma_f32_16x16x32_bf16(
                        af[mt], bfr[nt], acc[mt][nt], 0, 0, 0);
            __builtin_amdgcn_s_setprio(0);
        }
        __builtin_amdgcn_sched_barrier(0);
        __builtin_amdgcn_s_barrier();          // all waves done reading buf[cur]
        __builtin_amdgcn_sched_barrier(0);
        if (t + 2 < NT) stage(t + 2, cur);     // overwrite buf[cur] (safe now)
        cur ^= 1;
    }
    // loop exit: all loads drained (vmcnt(0) at t=NT-1); all waves past
    // final barrier -> smem reusable by epilogue.

    // ---- epilogue (C frag layout: col=lane&15, row=(lane>>4)*4+reg) ----
    if (OMODE == 2) {
        float* kpart = (float*)Cp;
#pragma unroll
        for (int mt = 0; mt < 4; mt++) {
#pragma unroll
            for (int r = 0; r < 4; r++) {
                int row = m0 + wr * 64 + mt * 16 + q * 4 + r;
                float s = 0.f;
#pragma unroll
                for (int nt = 0; nt < 8; nt++) {
                    int col = n0 + wc * 128 + nt * 16 + lm;
                    float v = acc[mt][nt][r] + bias[col];
                    v = fmaxf(v, 0.f);
                    s = fmaf(v, kv[col], s);
                }
#pragma unroll
                for (int off = 8; off > 0; off >>= 1) s += __shfl_down(s, off);
                if (lm == 0) atomicAdd(&kpart[row], s);
            }
        }
    } else if (OMODE == 1) {
#pragma unroll
        for (int mt = 0; mt < 4; mt++) {
#pragma unroll
            for (int r = 0; r < 4; r++) {
                int row = m0 + wr * 64 + mt * 16 + q * 4 + r;
#pragma unroll
                for (int nt = 0; nt < 8; nt++) {
                    int col = n0 + wc * 128 + nt * 16 + lm;
                    float v = acc[mt][nt][r];
                    if (BIAS) v += bias[col];
                    if (col < relu_ncols) v = fmaxf(v, 0.f);
                    ((float*)Cp)[(size_t)row * ldc + col] = v;
                }
            }
        }
    } else {
        // bf16 C via LDS store-stage, two 128-row halves (64 KB overlay)
        u16* st = (u16*)smem;   // 128 x 256 bf16 = 64 KB
        u16* Cb = (u16*)Cp;
#pragma unroll
        for (int half = 0; half < 2; half++) {
            if ((wr >> 1) == half) {   // waves owning rows of this half
#pragma unroll
                for (int mt = 0; mt < 4; mt++) {
#pragma unroll
                    for (int r = 0; r < 4; r++) {
                        int rl = (wr & 1) * 64 + mt * 16 + q * 4 + r;   // 0..127
                        int rg = m0 + half * 128 + rl;
                        float scale = 1.0f;
                        if (INVK) scale = 1.0f / kv[rg];
#pragma unroll
                        for (int nt = 0; nt < 8; nt++) {
                            int cl = wc * 128 + nt * 16 + lm;
                            int cg = n0 + cl;
                            float v = acc[mt][nt][r];
                            if (BIAS) v += bias[cg];
                            if (ACCIN) {
                                u16 raw = accin[(size_t)rg * ldacc + cg];
                                union { u16 u; bf16 h; } cu; cu.u = raw;
                                v += __bfloat162float(cu.h);
                            }
                            if (INVK) v *= scale;
                            if (cg < relu_ncols) v = fmaxf(v, 0.f);
                            union { u16 u; bf16 h; } ou; ou.h = __float2bfloat16(v);
                            st[rl * 256 + cl] = ou.u;
                        }
                    }
                }
            }
            __syncthreads();
            // 512 threads copy 128x256 u16 = 4096 uint4; 8 per thread
#pragma unroll
            for (int c = 0; c < 8; c++) {
                int idx = tid + c * 512;              // 0..4095
                int rl = idx >> 5, cl = (idx & 31) * 8;
                *(uint4*)(Cb + (size_t)(m0 + half * 128 + rl) * ldc + n0 + cl)
                    = ((const uint4*)st)[idx];
            }
            __syncthreads();
        }
    }
}

// 256² pipelined wrapper: 1-D grid (multiple of 8), XCD-chunked swizzle,
// NCH = number of 256-col N-chunks.
template<int OMODE, int BIAS, int INVK, int ACCIN, int NCH>
__global__ __launch_bounds__(512, 2) void mgemm256(
    const bf16* __restrict__ Ap, const u16* __restrict__ accin,
    const bf16* __restrict__ W, const float* __restrict__ bias,
    const float* __restrict__ kv, void* __restrict__ Cp,
    int K, int lda, int ldw, int ldc, int ldacc, int relu_ncols)
{
    __shared__ __align__(16) char smem[131072];
    const int bid = blockIdx.x;
    const int cpx = gridDim.x >> 3;
    const int wg = (bid & 7) * cpx + (bid >> 3);
    const int nc = wg % NCH, mc = wg / NCH;
    gemm_body256<OMODE, BIAS, INVK, ACCIN>(
        smem, mc * 256, nc * 256,
        Ap, accin, W, bias, kv, Cp, K, lda, ldw, ldc, ldacc, relu_ncols);
}

// ---------------------------------------------------------------------------
// 128x128 2-barrier GEMM body (R7-proven, 4 waves, 3 blocks/CU) — used for
// the small-N GEMMs (CB, D2) where 128-wide N-chunks give better grid shape.
// ---------------------------------------------------------------------------
template<int OMODE, int BIAS, int INVK, int ACCIN>
__device__ __forceinline__ void gemm_body128(
    char* smem, int m0, int n0,
    const bf16* __restrict__ A, const u16* __restrict__ accin,
    const bf16* __restrict__ W, const float* __restrict__ bias,
    const float* __restrict__ kv, void* __restrict__ Cp,
    int K, int lda, int ldw, int ldc, int ldacc, int relu_ncols)
{
    bf16* sA = (bf16*)smem;               // 128 x 64 = 16 KB
    bf16* sB = (bf16*)(smem + 16384);     // 128 x 64 = 16 KB

    const int tid = threadIdx.x;
    const int wv = tid >> 6, ln = tid & 63;
    const int wr = wv >> 1, wc = wv & 1;
    const int lm = ln & 15, q = ln >> 4;

    f32x4 acc[4][4];
#pragma unroll
    for (int i = 0; i < 4; i++)
#pragma unroll
        for (int j = 0; j < 4; j++)
            acc[i][j] = (f32x4){0.f, 0.f, 0.f, 0.f};

    for (int k0 = 0; k0 < K; k0 += 64) {
#pragma unroll
        for (int i = 0; i < 4; i++) {
            int c = wv * 256 + i * 64 + ln;
            int row = c >> 3;
            int g = (c & 7) ^ (row & 7);
            async_copy16(A + (size_t)(m0 + row) * lda + k0 + g * 8, &sA[c * 8]);
        }
#pragma unroll
        for (int i = 0; i < 4; i++) {
            int c = wv * 256 + i * 64 + ln;
            int row = c >> 3;
            int g = (c & 7) ^ (row & 7);
            async_copy16(W + (size_t)(n0 + row) * ldw + k0 + g * 8, &sB[c * 8]);
        }
        __syncthreads();

#pragma unroll
        for (int kk = 0; kk < 2; kk++) {
            frag8 af[4], bfr[4];
#pragma unroll
            for (int t = 0; t < 4; t++) {
                int r = wr * 64 + t * 16 + lm;
                af[t] = *(const frag8*)&sA[r * 64 + (((kk * 4 + q) ^ (r & 7)) * 8)];
            }
#pragma unroll
            for (int t = 0; t < 4; t++) {
                int n = wc * 64 + t * 16 + lm;
                bfr[t] = *(const frag8*)&sB[n * 64 + (((kk * 4 + q) ^ (n & 7)) * 8)];
            }
#pragma unroll
            for (int mt = 0; mt < 4; mt++)
#pragma unroll
                for (int nt = 0; nt < 4; nt++)
                    acc[mt][nt] = __builtin_amdgcn_mfma_f32_16x16x32_bf16(
                        af[mt], bfr[nt], acc[mt][nt], 0, 0, 0);
        }
        __syncthreads();
    }

    if (OMODE == 1) {
#pragma unroll
        for (int mt = 0; mt < 4; mt++) {
#pragma unroll
            for (int r = 0; r < 4; r++) {
                int row = m0 + wr * 64 + mt * 16 + q * 4 + r;
#pragma unroll
                for (int nt = 0; nt < 4; nt++) {
                    int col = n0 + wc * 64 + nt * 16 + lm;
                    float v = acc[mt][nt][r];
                    if (BIAS) v += bias[col];
                    if (col < relu_ncols) v = fmaxf(v, 0.f);
                    ((float*)Cp)[(size_t)row * ldc + col] = v;
                }
            }
        }
    } else {
        u16* st = (u16*)smem;   // 128 x 128 bf16 = 32 KB (post-barrier overlay)
#pragma unroll
        for (int mt = 0; mt < 4; mt++) {
#pragma unroll
            for (int r = 0; r < 4; r++) {
                int rl = wr * 64 + mt * 16 + q * 4 + r;
                int rg = m0 + rl;
                float scale = 1.0f;
                if (INVK) scale = 1.0f / kv[rg];
#pragma unroll
                for (int nt = 0; nt < 4; nt++) {
                    int cl = wc * 64 + nt * 16 + lm;
                    int cg = n0 + cl;
                    float v = acc[mt][nt][r];
                    if (BIAS) v += bias[cg];
                    if (ACCIN) {
                        u16 raw = accin[(size_t)rg * ldacc + cg];
                        union { u16 u; bf16 h; } cu; cu.u = raw;
                        v += __bfloat162float(cu.h);
                    }
                    if (INVK) v *= scale;
                    if (cg < relu_ncols) v = fmaxf(v, 0.f);
                    union { u16 u; bf16 h; } ou; ou.h = __float2bfloat16(v);
                    st[rl * 128 + cl] = ou.u;
                }
            }
        }
        __syncthreads();
        u16* Cb = (u16*)Cp;
#pragma unroll
        for (int c = 0; c < 8; c++) {
            int idx = tid + c * 256;              // 0..2047 chunks of 8 bf16
            int rl = idx >> 4, cl = (idx & 15) * 8;
            *(uint4*)(Cb + (size_t)(m0 + rl) * ldc + n0 + cl) = ((const uint4*)st)[idx];
        }
    }
}

template<int OMODE, int BIAS, int INVK, int ACCIN, int NCH>
__global__ __launch_bounds__(256, 3) void mgemm128(
    const bf16* __restrict__ Ap, const u16* __restrict__ accin,
    const bf16* __restrict__ W, const float* __restrict__ bias,
    const float* __restrict__ kv, void* __restrict__ Cp,
    int K, int lda, int ldw, int ldc, int ldacc, int relu_ncols)
{
    __shared__ __align__(16) char smem[32768];
    const int bid = blockIdx.x;
    const int cpx = gridDim.x >> 3;
    const int wg = (bid & 7) * cpx + (bid >> 3);
    const int nc = wg % NCH, mc = wg / NCH;
    gemm_body128<OMODE, BIAS, INVK, ACCIN>(
        smem, mc * 128, nc * 128,
        Ap, accin, W, bias, kv, Cp, K, lda, ldw, ldc, ldacc, relu_ncols);
}

// fusedA: bid<4 -> Wcomb2 = Wk1b @ We2 (M=512 N=512 K=1024), first so it
// hides under E1. bid>=4 -> E1||K1a over bf16 x (K=256), swizzled.
__global__ __launch_bounds__(512, 2) void fusedA_kernel(
    const bf16* __restrict__ xb, const bf16* __restrict__ wstk,
    const float* __restrict__ bstk, bf16* __restrict__ bufA,
    const bf16* __restrict__ wk1b, const bf16* __restrict__ we2t,
    bf16* __restrict__ wcomb2)
{
    __shared__ __align__(16) char smem[131072];
    const int bid = blockIdx.x;
    if (bid < 4) {
        gemm_body256<0, 0, 0, 0>(smem, (bid >> 1) * 256, (bid & 1) * 256,
            wk1b, nullptr, we2t, nullptr, nullptr, wcomb2, 1024, 1280, 1024, 512, 0, 0);
    } else {
        const int b = bid - 4;                        // [0, 512)
        const int wg = (b & 7) * 64 + (b >> 3);
        const int mc = wg >> 2, nc = wg & 3;          // 128 M-chunks x 4 N-chunks
        gemm_body256<0, 1, 0, 0>(smem, mc * 256, nc * 256,
            xb, nullptr, wstk, bstk, nullptr, bufA, 256, 256, 256, 1024, 0, 512);
    }
}

// fusedB: c in [0,6): c<4 -> E2 n-chunk c; c>=4 -> K1b' n-chunk c-4.
__global__ __launch_bounds__(512, 2) void fusedB_kernel(
    const bf16* __restrict__ bufA, const bf16* __restrict__ we2w,
    const float* __restrict__ be2, bf16* __restrict__ bufB,
    const bf16* __restrict__ wcomb2, const float* __restrict__ bconst,
    bf16* __restrict__ bufC)
{
    __shared__ __align__(16) char smem[131072];
    const int bid = blockIdx.x;                       // [0, 768)
    const int wg = (bid & 7) * 96 + (bid >> 3);
    const int nc = wg % 6, mc = wg / 6;
    if (nc < 4) {
        gemm_body256<0, 1, 0, 0>(smem, mc * 256, nc * 256,
            bufA, nullptr, we2w, be2, nullptr, bufB, 512, 1024, 512, 1024, 0, 0);
    } else {
        gemm_body256<0, 1, 0, 1>(smem, mc * 256, (nc - 4) * 256,
            bufA, (const u16*)bufA + 512, wcomb2, bconst, nullptr, bufC,
            512, 1024, 512, 512, 1024, 1 << 30);
    }
}

// ---------------------------------------------------------------------------
// khot + kfinal fused (R1/R7-proven): wave-per-row, 2x8-bit radix with
// 8 per-lane-group sub-histograms (264-stride bank skew).
// ---------------------------------------------------------------------------
#define KH_GS 264

__device__ inline void suffix_pick(const unsigned* h, int lane, unsigned target,
                                   unsigned& bucket, unsigned& rem)
{
    uint4 hv = make_uint4(0u, 0u, 0u, 0u);
#pragma unroll
    for (int g = 0; g < 8; g++) {
        uint4 t = *(const uint4*)(h + g * KH_GS + lane * 4);
        hv.x += t.x; hv.y += t.y; hv.z += t.z; hv.w += t.w;
    }
    unsigned local = hv.x + hv.y + hv.z + hv.w;
    unsigned incl = local;
#pragma unroll
    for (int off = 1; off < 64; off <<= 1) {
        unsigned t = __shfl_down(incl, off);
        if (lane + off < 64) incl += t;
    }
    unsigned higher = incl - local;
    unsigned s3 = higher + hv.w;
    unsigned s2 = s3 + hv.z;
    unsigned s1 = s2 + hv.y;
    unsigned s0 = s1 + hv.x;
    unsigned suf[5] = {s0, s1, s2, s3, higher};
    int bj = -1; unsigned rm = 0;
#pragma unroll
    for (int j = 0; j < 4; j++)
        if (suf[j] >= target && suf[j + 1] < target) { bj = j; rm = target - suf[j + 1]; }
    unsigned long long mk = __ballot(bj >= 0);
    int src = (int)__ffsll((unsigned long long)mk) - 1;
    bucket = __shfl((unsigned)(lane * 4 + bj), src);
    rem    = __shfl(rm, src);
}

__device__ inline void hist_zero(unsigned* h, int lane) {
    uint4* h4 = (uint4*)h;                 // 8*264 u32 = 528 uint4
#pragma unroll
    for (int i = 0; i < 8; i++) h4[lane + i * 64] = make_uint4(0u, 0u, 0u, 0u);
    if (lane < 16) h4[512 + lane] = make_uint4(0u, 0u, 0u, 0u);
}

__global__ __launch_bounds__(256) void khot_kernel(
    u16* __restrict__ lb, const float* __restrict__ kpart,
    const float* __restrict__ b3, const float* __restrict__ kscale,
    float* __restrict__ mf, float* __restrict__ kout, float* __restrict__ scl)
{
    __shared__ unsigned hist[4][8 * KH_GS];   // 4 waves x 8.25 KB = 33 KB
    const int w = threadIdx.x >> 6, lane = threadIdx.x & 63;
    const int row = blockIdx.x * 4 + w;
    u16* rp = lb + (size_t)row * QDIM;
    float* mfp = mf + (size_t)row * QDIM;

    float z = kpart[row] + b3[0];
    float kk = 1024.0f / (1.0f + expf(-z));
    float sc = 1.0f / (1.0f + expf(-kscale[0]));
    float kvv = fminf(fmaxf(kk * sc * 2.0f, 1.0f), 1024.0f);
    if (lane == 0) kout[row] = kvv;
    if (row == 0 && lane == 0) scl[0] = 0.0f;

    u16x8 v0 = *(const u16x8*)(rp + lane * 8);
    u16x8 v1 = *(const u16x8*)(rp + 512 + lane * 8);
    unsigned key[2][8];
#pragma unroll
    for (int j = 0; j < 8; j++) {
        unsigned a = v0[j], b = v1[j];
        key[0][j] = (a & 0x8000u) ? (~a & 0xffffu) : (a | 0x8000u);
        key[1][j] = (b & 0x8000u) ? (~b & 0xffffu) : (b | 0x8000u);
    }
    int mi = (int)ceilf(kvv);
    mi = mi < 1 ? 1 : (mi > QDIM ? QDIM : mi);
    const unsigned m = (unsigned)mi;
    unsigned* h = hist[w];
    unsigned* hg = h + (lane >> 3) * KH_GS;   // this lane's sub-histogram

    hist_zero(h, lane);
    __threadfence_block();
#pragma unroll
    for (int c = 0; c < 2; c++)
#pragma unroll
        for (int j = 0; j < 8; j++)
            atomicAdd(&hg[key[c][j] >> 8], 1u);
    __threadfence_block();
    unsigned hi, rem1;
    suffix_pick(h, lane, m, hi, rem1);

    hist_zero(h, lane);
    __threadfence_block();
#pragma unroll
    for (int c = 0; c < 2; c++)
#pragma unroll
        for (int j = 0; j < 8; j++)
            if ((key[c][j] >> 8) == hi) atomicAdd(&hg[key[c][j] & 255u], 1u);
    __threadfence_block();
    unsigned lo, need;
    suffix_pick(h, lane, rem1, lo, need);

    const unsigned um = (hi << 8) | lo;

    unsigned cnt0 = 0, cnt1 = 0;
#pragma unroll
    for (int j = 0; j < 8; j++) { cnt0 += (key[0][j] == um); cnt1 += (key[1][j] == um); }
    unsigned pack = cnt0 | (cnt1 << 16);
    unsigned incl = pack;
#pragma unroll
    for (int off = 1; off < 64; off <<= 1) {
        unsigned t = __shfl_up(incl, off);
        if (lane >= off) incl += t;
    }
    unsigned excl = incl - pack;
    unsigned tot0 = __shfl(incl, 63) & 0xffffu;
    unsigned r0 = excl & 0xffffu;
    unsigned r1 = tot0 + (excl >> 16);

    float of[2][8];
    u16x8 mb0, mb1;
#pragma unroll
    for (int j = 0; j < 8; j++) {
        unsigned kv_ = key[0][j];
        bool s;
        if (kv_ > um) s = true;
        else if (kv_ == um) { s = (r0 < need); r0++; }
        else s = false;
        of[0][j] = s ? 1.0f : 0.0f;
        mb0[j] = s ? (u16)0x3F80 : (u16)0;
    }
#pragma unroll
    for (int j = 0; j < 8; j++) {
        unsigned kv_ = key[1][j];
        bool s;
        if (kv_ > um) s = true;
        else if (kv_ == um) { s = (r1 < need); r1++; }
        else s = false;
        of[1][j] = s ? 1.0f : 0.0f;
        mb1[j] = s ? (u16)0x3F80 : (u16)0;
    }
    *(float4*)(mfp + lane * 8)           = make_float4(of[0][0], of[0][1], of[0][2], of[0][3]);
    *(float4*)(mfp + lane * 8 + 4)       = make_float4(of[0][4], of[0][5], of[0][6], of[0][7]);
    *(float4*)(mfp + 512 + lane * 8)     = make_float4(of[1][0], of[1][1], of[1][2], of[1][3]);
    *(float4*)(mfp + 512 + lane * 8 + 4) = make_float4(of[1][4], of[1][5], of[1][6], of[1][7]);
    *(u16x8*)(rp + lane * 8)       = mb0;
    *(u16x8*)(rp + 512 + lane * 8) = mb1;
}

// ---------------------------------------------------------------------------
extern "C" void kernel_launch(void* const* d_in, const int* in_sizes, int n_in,
                              void* d_out, int out_size, void* d_ws, size_t ws_size,
                              hipStream_t stream) {
    const float* x     = (const float*)d_in[0];
    const float* W_e1  = (const float*)d_in[1];
    const float* b_e1  = (const float*)d_in[2];
    const float* W_e2  = (const float*)d_in[3];
    const float* b_e2  = (const float*)d_in[4];
    const float* W_cb  = (const float*)d_in[5];
    const float* W_d1  = (const float*)d_in[6];
    const float* b_d1  = (const float*)d_in[7];
    const float* W_d2  = (const float*)d_in[8];
    const float* b_d2  = (const float*)d_in[9];
    const float* W_k1  = (const float*)d_in[10];
    const float* b_k1  = (const float*)d_in[11];
    const float* W_k2  = (const float*)d_in[12];
    const float* b_k2  = (const float*)d_in[13];
    const float* W_k3  = (const float*)d_in[14];
    const float* b_k3  = (const float*)d_in[15];
    const float* k_scl = (const float*)d_in[16];

    float* out   = (float*)d_out;
    float* recon = out;
    float* maskf = out + OUT_KHOT_OFF;
    float* scl   = out + OUT_SCALAR_OFF;
    float* kout  = out + OUT_K_OFF;

    char* ws = (char*)d_ws;
    bf16* wb_k1  = (bf16*)(ws + WS_WK1);
    bf16* wb_e2  = (bf16*)(ws + WS_WE2);
    bf16* wb_cb  = (bf16*)(ws + WS_WCB);
    bf16* wb_d1  = (bf16*)(ws + WS_WD1);
    bf16* wb_d2  = (bf16*)(ws + WS_WD2);
    bf16* wb_k2  = (bf16*)(ws + WS_WK2);
    bf16* wstk   = (bf16*)(ws + WS_WSTK);
    float* bstk  = (float*)(ws + WS_BSTK);
    float* kpart = (float*)(ws + WS_KPART);
    bf16* bufA   = (bf16*)(ws + WS_BUFA);
    bf16* bufB   = (bf16*)(ws + WS_BUFB);
    bf16* bufC   = (bf16*)(ws + WS_BUFC);
    bf16* bufX   = (bf16*)(ws + WS_BUFX);
    bf16* we2t   = (bf16*)(ws + WS_WE2T);
    bf16* wcomb2 = (bf16*)(ws + WS_WCOMB2);
    float* bconst = (float*)(ws + WS_BCONST);

    const dim3 blk(256);
    const dim3 blk512(512);
    const int FULL = 1 << 30;

    // prep: conversions (incl. x->bf16) + stacked W/b + We2T + bconst + kpart
    cvt_kernel<<<dim3(CVT_GRID), blk, 0, stream>>>(
        W_e1, W_e2, W_cb, W_d1, W_d2, W_k1, W_k2, b_e1, b_e2, b_k1, x, ws);

    // Wcomb2 (4 blocks, overlapped) + E1||K1a (512 blocks, swizzled)
    fusedA_kernel<<<dim3(516), blk512, 0, stream>>>(
        bufX, wstk, bstk, bufA, wb_k1 + 256, we2t, wcomb2);

    // E2 + K1b' merged (768 blocks)
    fusedB_kernel<<<dim3(768), blk512, 0, stream>>>(
        bufA, wb_e2, b_e2, bufB, wcomb2, bconst, bufC);

    // K2+kdot: kpart[row] += relu(hk1 @ Wk2^T + b_k2) . w3   (256 blocks)
    mgemm256<2, 1, 0, 0, 2><<<dim3(256), blk512, 0, stream>>>(
        bufC, nullptr, wb_k2, b_k2, W_k3, kpart, 512, 512, 512, 512, 0, FULL);

    // khot (+kfinal): logits -> fp32 mask (d_out) + bf16 mask; k -> kout/scl
    khot_kernel<<<dim3(Bn / 4), blk, 0, stream>>>(
        (u16*)bufB, kpart, b_k3, k_scl, maskf, kout, scl);

    // CB: q = (mask/k) @ Wcb^T -> bufA  (128² body, 512 blocks, 3/CU)
    mgemm128<0, 0, 1, 0, 2><<<dim3(512), blk, 0, stream>>>(
        bufB, nullptr, wb_cb, nullptr, kout, bufA, 1024, 1024, 1024, 256, 0, 0);

    // D1: hd1 = relu(q @ Wd1^T + b_d1) -> bufC   (256² pipelined, 256 blocks)
    mgemm256<0, 1, 0, 0, 2><<<dim3(256), blk512, 0, stream>>>(
        bufA, nullptr, wb_d1, b_d1, nullptr, bufC, 256, 256, 256, 512, 0, FULL);

    // D2: recon = hd1 @ Wd2^T + b_d2 -> d_out (fp32)  (128² body, 512 blocks)
    mgemm128<1, 1, 0, 0, 2><<<dim3(512), blk, 0, stream>>>(
        bufC, nullptr, wb_d2, b_d2, nullptr, recon, 512, 512, 512, 256, 0, 0);
}

// Round 11
// 450.155 us; speedup vs baseline: 1.2656x; 1.0406x over previous
//
#include <hip/hip_runtime.h>
#include <hip/hip_bf16.h>
#include <math.h>

typedef __hip_bfloat16 bf16;
typedef unsigned short u16;
using frag8 = __attribute__((ext_vector_type(8))) short;   // 8 bf16 = 4 VGPRs
using f32x4 = __attribute__((ext_vector_type(4))) float;   // MFMA accumulator
using u16x8 = __attribute__((ext_vector_type(8))) unsigned short;

// Problem constants
#define Bn      32768
#define IN_DIM  256
#define N_HDIM  512
#define QDIM    1024
#define N_EMBD  256

// Output layout (float32): recon [B*256] | khot [B*1024] | scalar [1] | k [B]
#define OUT_KHOT_OFF   ((size_t)Bn * IN_DIM)
#define OUT_SCALAR_OFF (OUT_KHOT_OFF + (size_t)Bn * QDIM)
#define OUT_K_OFF      (OUT_SCALAR_OFF + 1)

// Workspace layout (bytes)
#define WS_WK1    0                                   // 512x1280 bf16 (full)
#define WS_WE2    (WS_WK1 + 512*1280*2)               // 1024x512
#define WS_WCB    (WS_WE2 + 1024*512*2)               // 256x1024
#define WS_WD1    (WS_WCB + 256*1024*2)               // 512x256
#define WS_WD2    (WS_WD1 + 512*256*2)                // 256x512
#define WS_WK2    (WS_WD2 + 256*512*2)                // 512x512
#define WS_WSTK   (WS_WK2 + 512*512*2)                // 1024x256 [We1 ; Wk1[:,:256]]
#define WS_BSTK   (WS_WSTK + 1024*256*2)              // 1024 fp32 [b_e1 | 0]
#define WS_KPART  (WS_BSTK + 1024*4)                  // Bn fp32 (zeroed by cvt)
#define WS_BUFA   (WS_KPART + (size_t)Bn*4)           // Bn x 1024 bf16: [h1|kp1] -> q
#define WS_BUFB   (WS_BUFA + (size_t)Bn*1024*2)       // Bn x 1024 bf16: logits -> mask
#define WS_BUFC   (WS_BUFB + (size_t)Bn*1024*2)       // Bn x 512 bf16: xb -> hk1 -> hd1
#define WS_WE2T   (WS_BUFC + (size_t)Bn*512*2)        // 512x1024 bf16 (We2 transposed)
#define WS_WCOMB2 (WS_WE2T + 512*1024*2)              // 512x512 bf16 (Wk1b @ We2)
#define WS_BCONST (WS_WCOMB2 + 512*512*2)             // 512 fp32
// bf16 x (32768x256 = 16.8 MB) overlays bufC: written by cvt, read by E1
// (fusedA); fusedB overwrites the region with hk1 only AFTER E1 completes.
#define WS_BUFX   WS_BUFC

// cvt grid segmentation
#define CVT_BASE  2177
#define CVT_T     512
#define CVT_BC    128
#define CVT_KZ    32
#define CVT_X     4096
#define CVT_GRID  (CVT_BASE + CVT_T + CVT_BC + CVT_KZ + CVT_X)   // 6945

__device__ inline void async_copy16(const void* g, void* l) {
    __builtin_amdgcn_global_load_lds(
        (const __attribute__((address_space(1))) void*)g,
        (__attribute__((address_space(3))) void*)l, 16, 0, 0);
}

__device__ inline void cv4(bf16* d, float4 v) {
    union { short4 s; bf16 h[4]; } u;
    u.h[0] = __float2bfloat16(v.x); u.h[1] = __float2bfloat16(v.y);
    u.h[2] = __float2bfloat16(v.z); u.h[3] = __float2bfloat16(v.w);
    *(short4*)d = u.s;
}

// ---------------------------------------------------------------------------
// One-shot prep: all weight bf16 conversions, stacked [We1;Wk1a] + bias,
// We2 transpose, bconst = Wk1b . b_e2 + b_k1, kpart zeroing, x -> bf16.
// ---------------------------------------------------------------------------
__global__ __launch_bounds__(256) void cvt_kernel(
    const float* __restrict__ We1, const float* __restrict__ We2,
    const float* __restrict__ Wcb, const float* __restrict__ Wd1,
    const float* __restrict__ Wd2, const float* __restrict__ Wk1,
    const float* __restrict__ Wk2, const float* __restrict__ be1,
    const float* __restrict__ be2, const float* __restrict__ bk1,
    const float* __restrict__ x, char* __restrict__ ws)
{
    const int bx = blockIdx.x, tid = threadIdx.x;
    if (bx < CVT_BASE) {
        int id = bx * 256 + tid;
        const float* src; bf16* dst; int off;
        if      (id < 163840) { src = Wk1; dst = (bf16*)(ws + WS_WK1); off = id; }
        else if (id < 294912) { src = We2; dst = (bf16*)(ws + WS_WE2); off = id - 163840; }
        else if (id < 360448) { src = Wcb; dst = (bf16*)(ws + WS_WCB); off = id - 294912; }
        else if (id < 393216) { src = Wd1; dst = (bf16*)(ws + WS_WD1); off = id - 360448; }
        else if (id < 425984) { src = Wd2; dst = (bf16*)(ws + WS_WD2); off = id - 393216; }
        else if (id < 491520) { src = Wk2; dst = (bf16*)(ws + WS_WK2); off = id - 425984; }
        else if (id < 524288) { src = We1; dst = (bf16*)(ws + WS_WSTK); off = id - 491520; }
        else if (id < 557056) {           // Wk1[:, :256] -> wstk rows 512..1023
            int l = id - 524288; int r = l >> 6, c4 = (l & 63) * 4;
            float4 v = *(const float4*)(Wk1 + (size_t)r * 1280 + c4);
            cv4((bf16*)(ws + WS_WSTK) + 131072 + r * 256 + c4, v);
            return;
        } else {                           // bias_stk: [b_e1 | zeros], fp32
            int l = id - 557056;
            float4 v = (l < 128) ? *(const float4*)(be1 + l * 4)
                                 : make_float4(0.f, 0.f, 0.f, 0.f);
            *(float4*)((float*)(ws + WS_BSTK) + l * 4) = v;
            return;
        }
        float4 v = *(const float4*)(src + (size_t)off * 4);
        cv4(dst + (size_t)off * 4, v);
    } else if (bx < CVT_BASE + CVT_T) {
        int local = (bx - CVT_BASE) * 256 + tid;
        int n = local & 511;
        int k = (local >> 9) * 4;
        float4 v;
        v.x = We2[(size_t)(k + 0) * 512 + n];
        v.y = We2[(size_t)(k + 1) * 512 + n];
        v.z = We2[(size_t)(k + 2) * 512 + n];
        v.w = We2[(size_t)(k + 3) * 512 + n];
        cv4((bf16*)(ws + WS_WE2T) + (size_t)n * 1024 + k, v);
    } else if (bx < CVT_BASE + CVT_T + CVT_BC) {
        int r = (bx - CVT_BASE - CVT_T) * 4 + (tid >> 6);
        int lane = tid & 63;
        const float* wr = Wk1 + (size_t)r * 1280 + 256;
        float s = 0.f;
#pragma unroll
        for (int t = 0; t < 16; t++) {
            int j = lane + t * 64;
            s = fmaf(wr[j], be2[j], s);
        }
#pragma unroll
        for (int off = 32; off > 0; off >>= 1) s += __shfl_down(s, off);
        if (lane == 0) ((float*)(ws + WS_BCONST))[r] = s + bk1[r];
    } else if (bx < CVT_BASE + CVT_T + CVT_BC + CVT_KZ) {
        int idx = ((bx - CVT_BASE - CVT_T - CVT_BC) * 256 + tid) * 4;
        *(float4*)((float*)(ws + WS_KPART) + idx) = make_float4(0.f, 0.f, 0.f, 0.f);
    } else {
        // x (32768x256 fp32) -> bf16 bufX; 8 elems/thread, 16B stores
        int id = (bx - CVT_BASE - CVT_T - CVT_BC - CVT_KZ) * 256 + tid;
        const float* src = x + (size_t)id * 8;
        float4 v0 = *(const float4*)src;
        float4 v1 = *(const float4*)(src + 4);
        union { frag8 s; bf16 h[8]; } u;
        u.h[0] = __float2bfloat16(v0.x); u.h[1] = __float2bfloat16(v0.y);
        u.h[2] = __float2bfloat16(v0.z); u.h[3] = __float2bfloat16(v0.w);
        u.h[4] = __float2bfloat16(v1.x); u.h[5] = __float2bfloat16(v1.y);
        u.h[6] = __float2bfloat16(v1.z); u.h[7] = __float2bfloat16(v1.w);
        *(frag8*)((bf16*)(ws + WS_BUFX) + (size_t)id * 8) = u.s;
    }
}

// ---------------------------------------------------------------------------
// 128x128 2-barrier GEMM body (R7-measured best for short-K / small-N GEMMs):
// 4 waves, 32 KB LDS, 3 blocks/CU -> cross-block latency hiding for free.
// OMODE: 0 = bf16 C (coalesced); 1 = fp32 C; 2 = kdot epilogue (atomicAdd).
// ---------------------------------------------------------------------------
template<int OMODE, int BIAS, int INVK, int ACCIN>
__device__ __forceinline__ void gemm_body(
    char* smem, int m0, int n0,
    const bf16* __restrict__ A, const u16* __restrict__ accin,
    const bf16* __restrict__ W, const float* __restrict__ bias,
    const float* __restrict__ kv, void* __restrict__ Cp,
    int K, int lda, int ldw, int ldc, int ldacc, int relu_ncols)
{
    bf16* sA = (bf16*)smem;               // 128 x 64 = 16 KB
    bf16* sB = (bf16*)(smem + 16384);     // 128 x 64 = 16 KB

    const int tid = threadIdx.x;
    const int wv = tid >> 6, ln = tid & 63;
    const int wr = wv >> 1, wc = wv & 1;
    const int lm = ln & 15, q = ln >> 4;

    f32x4 acc[4][4];
#pragma unroll
    for (int i = 0; i < 4; i++)
#pragma unroll
        for (int j = 0; j < 4; j++)
            acc[i][j] = (f32x4){0.f, 0.f, 0.f, 0.f};

    for (int k0 = 0; k0 < K; k0 += 64) {
#pragma unroll
        for (int i = 0; i < 4; i++) {
            int c = wv * 256 + i * 64 + ln;
            int row = c >> 3;
            int g = (c & 7) ^ (row & 7);
            async_copy16(A + (size_t)(m0 + row) * lda + k0 + g * 8, &sA[c * 8]);
        }
#pragma unroll
        for (int i = 0; i < 4; i++) {
            int c = wv * 256 + i * 64 + ln;
            int row = c >> 3;
            int g = (c & 7) ^ (row & 7);
            async_copy16(W + (size_t)(n0 + row) * ldw + k0 + g * 8, &sB[c * 8]);
        }
        __syncthreads();

#pragma unroll
        for (int kk = 0; kk < 2; kk++) {
            frag8 af[4], bfr[4];
#pragma unroll
            for (int t = 0; t < 4; t++) {
                int r = wr * 64 + t * 16 + lm;
                af[t] = *(const frag8*)&sA[r * 64 + (((kk * 4 + q) ^ (r & 7)) * 8)];
            }
#pragma unroll
            for (int t = 0; t < 4; t++) {
                int n = wc * 64 + t * 16 + lm;
                bfr[t] = *(const frag8*)&sB[n * 64 + (((kk * 4 + q) ^ (n & 7)) * 8)];
            }
#pragma unroll
            for (int mt = 0; mt < 4; mt++)
#pragma unroll
                for (int nt = 0; nt < 4; nt++)
                    acc[mt][nt] = __builtin_amdgcn_mfma_f32_16x16x32_bf16(
                        af[mt], bfr[nt], acc[mt][nt], 0, 0, 0);
        }
        __syncthreads();
    }

    // ---- epilogue (C frag layout: col=lane&15, row=(lane>>4)*4+reg) ----
    if (OMODE == 2) {
        float* kpart = (float*)Cp;
#pragma unroll
        for (int mt = 0; mt < 4; mt++) {
#pragma unroll
            for (int r = 0; r < 4; r++) {
                int row = m0 + wr * 64 + mt * 16 + q * 4 + r;
                float s = 0.f;
#pragma unroll
                for (int nt = 0; nt < 4; nt++) {
                    int col = n0 + wc * 64 + nt * 16 + lm;
                    float v = acc[mt][nt][r] + bias[col];
                    v = fmaxf(v, 0.f);
                    s = fmaf(v, kv[col], s);
                }
#pragma unroll
                for (int off = 8; off > 0; off >>= 1) s += __shfl_down(s, off);
                if (lm == 0) atomicAdd(&kpart[row], s);
            }
        }
    } else if (OMODE == 1) {
#pragma unroll
        for (int mt = 0; mt < 4; mt++) {
#pragma unroll
            for (int r = 0; r < 4; r++) {
                int row = m0 + wr * 64 + mt * 16 + q * 4 + r;
#pragma unroll
                for (int nt = 0; nt < 4; nt++) {
                    int col = n0 + wc * 64 + nt * 16 + lm;
                    float v = acc[mt][nt][r];
                    if (BIAS) v += bias[col];
                    if (col < relu_ncols) v = fmaxf(v, 0.f);
                    ((float*)Cp)[(size_t)row * ldc + col] = v;
                }
            }
        }
    } else {
        u16* st = (u16*)smem;   // 128 x 128 bf16 = 32 KB (post-barrier overlay)
#pragma unroll
        for (int mt = 0; mt < 4; mt++) {
#pragma unroll
            for (int r = 0; r < 4; r++) {
                int rl = wr * 64 + mt * 16 + q * 4 + r;
                int rg = m0 + rl;
                float scale = 1.0f;
                if (INVK) scale = 1.0f / kv[rg];
#pragma unroll
                for (int nt = 0; nt < 4; nt++) {
                    int cl = wc * 64 + nt * 16 + lm;
                    int cg = n0 + cl;
                    float v = acc[mt][nt][r];
                    if (BIAS) v += bias[cg];
                    if (ACCIN) {
                        u16 raw = accin[(size_t)rg * ldacc + cg];
                        union { u16 u; bf16 h; } cu; cu.u = raw;
                        v += __bfloat162float(cu.h);
                    }
                    if (INVK) v *= scale;
                    if (cg < relu_ncols) v = fmaxf(v, 0.f);
                    union { u16 u; bf16 h; } ou; ou.h = __float2bfloat16(v);
                    st[rl * 128 + cl] = ou.u;
                }
            }
        }
        __syncthreads();
        u16* Cb = (u16*)Cp;
#pragma unroll
        for (int c = 0; c < 8; c++) {
            int idx = tid + c * 256;              // 0..2047 chunks of 8 bf16
            int rl = idx >> 4, cl = (idx & 15) * 8;
            *(uint4*)(Cb + (size_t)(m0 + rl) * ldc + n0 + cl) = ((const uint4*)st)[idx];
        }
    }
}

template<int OMODE, int BIAS, int INVK, int ACCIN, int NCH>
__global__ __launch_bounds__(256, 3) void mgemm(
    const bf16* __restrict__ Ap, const u16* __restrict__ accin,
    const bf16* __restrict__ W, const float* __restrict__ bias,
    const float* __restrict__ kv, void* __restrict__ Cp,
    int K, int lda, int ldw, int ldc, int ldacc, int relu_ncols)
{
    __shared__ __align__(16) char smem[32768];
    const int bid = blockIdx.x;
    const int cpx = gridDim.x >> 3;
    const int wg = (bid & 7) * cpx + (bid >> 3);
    const int nc = wg % NCH, mc = wg / NCH;
    gemm_body<OMODE, BIAS, INVK, ACCIN>(
        smem, mc * 128, nc * 128,
        Ap, accin, W, bias, kv, Cp, K, lda, ldw, ldc, ldacc, relu_ncols);
}

// fusedA (R7-proven): bid<16 -> Wcomb2 = Wk1b @ We2 (first, hides under E1);
// bid>=16 -> E1||K1a over bf16 x (K=256), XCD-chunked swizzle.
__global__ __launch_bounds__(256, 3) void fusedA_kernel(
    const bf16* __restrict__ xb, const bf16* __restrict__ wstk,
    const float* __restrict__ bstk, bf16* __restrict__ bufA,
    const bf16* __restrict__ wk1b, const bf16* __restrict__ we2t,
    bf16* __restrict__ wcomb2)
{
    __shared__ __align__(16) char smem[32768];
    const int bid = blockIdx.x;
    if (bid < 16) {
        gemm_body<0, 0, 0, 0>(smem, (bid & 3) * 128, (bid >> 2) * 128,
            wk1b, nullptr, we2t, nullptr, nullptr, wcomb2, 1024, 1280, 1024, 512, 0, 0);
    } else {
        const int b = bid - 16;                       // [0, 2048)
        const int wg = (b & 7) * 256 + (b >> 3);
        const int mc = wg >> 3, nc = wg & 7;
        gemm_body<0, 1, 0, 0>(smem, mc * 128, nc * 128,
            xb, nullptr, wstk, bstk, nullptr, bufA, 256, 256, 256, 1024, 0, 512);
    }
}

// ---------------------------------------------------------------------------
// 256x256 PIPELINED GEMM body (R10-proven; used ONLY for fusedB where K=512
// depth + 768-block grid make the counted-vmcnt pipeline pay: R9's 2-barrier
// 256² fusedB was 124.5 us latency-bound @16% MfmaUtil; R10's pipeline moved
// it below the top-5 threshold). LDS 128 KB = double-buffered {A|B} x 2;
// vmcnt(8) keeps next tile's 8 loads in flight across both barriers;
// raw s_barrier + sched_barrier(0) pins; setprio(1) around MFMA cluster.
// ---------------------------------------------------------------------------
template<int OMODE, int BIAS, int INVK, int ACCIN>
__device__ __forceinline__ void gemm_body256(
    char* smem, int m0, int n0,
    const bf16* __restrict__ A, const u16* __restrict__ accin,
    const bf16* __restrict__ W, const float* __restrict__ bias,
    const float* __restrict__ kv, void* __restrict__ Cp,
    int K, int lda, int ldw, int ldc, int ldacc, int relu_ncols)
{
    const int tid = threadIdx.x;
    const int wv = tid >> 6, ln = tid & 63;
    const int wr = wv >> 1, wc = wv & 1;     // 4 M-waves x 2 N-waves
    const int lm = ln & 15, q = ln >> 4;

    f32x4 acc[4][8];
#pragma unroll
    for (int i = 0; i < 4; i++)
#pragma unroll
        for (int j = 0; j < 8; j++)
            acc[i][j] = (f32x4){0.f, 0.f, 0.f, 0.f};

    const int NT = K >> 6;

    auto stage = [&](int t, int b) {
        bf16* sA = (bf16*)(smem + b * 65536);
        bf16* sB = (bf16*)(smem + b * 65536 + 32768);
        const int k0 = t * 64;
#pragma unroll
        for (int i = 0; i < 4; i++) {
            int c = i * 512 + tid;            // 0..2047
            int row = c >> 3;                 // 0..255
            int g = (c & 7) ^ (row & 7);
            async_copy16(A + (size_t)(m0 + row) * lda + k0 + g * 8, &sA[c * 8]);
        }
#pragma unroll
        for (int i = 0; i < 4; i++) {
            int c = i * 512 + tid;
            int row = c >> 3;
            int g = (c & 7) ^ (row & 7);
            async_copy16(W + (size_t)(n0 + row) * ldw + k0 + g * 8, &sB[c * 8]);
        }
    };

    stage(0, 0);
    if (NT > 1) stage(1, 1);
    int cur = 0;
    for (int t = 0; t < NT; t++) {
        // wait for MY tile-t loads (8 oldest); tile-(t+1)'s 8 stay in flight
        if (t + 1 < NT) { asm volatile("s_waitcnt vmcnt(8)" ::: "memory"); }
        else            { asm volatile("s_waitcnt vmcnt(0)" ::: "memory"); }
        __builtin_amdgcn_s_barrier();          // all waves' tile-t data in LDS
        __builtin_amdgcn_sched_barrier(0);

        bf16* sA = (bf16*)(smem + cur * 65536);
        bf16* sB = (bf16*)(smem + cur * 65536 + 32768);
#pragma unroll
        for (int kk = 0; kk < 2; kk++) {
            frag8 af[4], bfr[8];
#pragma unroll
            for (int tt = 0; tt < 4; tt++) {
                int r = wr * 64 + tt * 16 + lm;
                af[tt] = *(const frag8*)&sA[r * 64 + (((kk * 4 + q) ^ (r & 7)) * 8)];
            }
#pragma unroll
            for (int tt = 0; tt < 8; tt++) {
                int n = wc * 128 + tt * 16 + lm;
                bfr[tt] = *(const frag8*)&sB[n * 64 + (((kk * 4 + q) ^ (n & 7)) * 8)];
            }
            __builtin_amdgcn_s_setprio(1);
#pragma unroll
            for (int mt = 0; mt < 4; mt++)
#pragma unroll
                for (int nt = 0; nt < 8; nt++)
                    acc[mt][nt] = __builtin_amdgcn_mfma_f32_16x16x32_bf16(
                        af[mt], bfr[nt], acc[mt][nt], 0, 0, 0);
            __builtin_amdgcn_s_setprio(0);
        }
        __builtin_amdgcn_sched_barrier(0);
        __builtin_amdgcn_s_barrier();          // all waves done reading buf[cur]
        __builtin_amdgcn_sched_barrier(0);
        if (t + 2 < NT) stage(t + 2, cur);     // overwrite buf[cur] (safe now)
        cur ^= 1;
    }

    // ---- epilogue: bf16 C via LDS store-stage, two 128-row halves ----
    u16* st = (u16*)smem;   // 128 x 256 bf16 = 64 KB overlay
    u16* Cb = (u16*)Cp;
#pragma unroll
    for (int half = 0; half < 2; half++) {
        if ((wr >> 1) == half) {   // waves owning rows of this half
#pragma unroll
            for (int mt = 0; mt < 4; mt++) {
#pragma unroll
                for (int r = 0; r < 4; r++) {
                    int rl = (wr & 1) * 64 + mt * 16 + q * 4 + r;   // 0..127
                    int rg = m0 + half * 128 + rl;
#pragma unroll
                    for (int nt = 0; nt < 8; nt++) {
                        int cl = wc * 128 + nt * 16 + lm;
                        int cg = n0 + cl;
                        float v = acc[mt][nt][r];
                        if (BIAS) v += bias[cg];
                        if (ACCIN) {
                            u16 raw = accin[(size_t)rg * ldacc + cg];
                            union { u16 u; bf16 h; } cu; cu.u = raw;
                            v += __bfloat162float(cu.h);
                        }
                        if (cg < relu_ncols) v = fmaxf(v, 0.f);
                        union { u16 u; bf16 h; } ou; ou.h = __float2bfloat16(v);
                        st[rl * 256 + cl] = ou.u;
                    }
                }
            }
        }
        __syncthreads();
        // 512 threads copy 128x256 u16 = 4096 uint4; 8 per thread
#pragma unroll
        for (int c = 0; c < 8; c++) {
            int idx = tid + c * 512;              // 0..4095
            int rl = idx >> 5, cl = (idx & 31) * 8;
            *(uint4*)(Cb + (size_t)(m0 + half * 128 + rl) * ldc + n0 + cl)
                = ((const uint4*)st)[idx];
        }
        __syncthreads();
    }
}

// fusedB: c in [0,6): c<4 -> E2 n-chunk c; c>=4 -> K1b' n-chunk c-4.
// 256² pipelined body; 768 blocks (128 mc x 6), XCD-chunked swizzle.
__global__ __launch_bounds__(512, 2) void fusedB_kernel(
    const bf16* __restrict__ bufA, const bf16* __restrict__ we2w,
    const float* __restrict__ be2, bf16* __restrict__ bufB,
    const bf16* __restrict__ wcomb2, const float* __restrict__ bconst,
    bf16* __restrict__ bufC)
{
    __shared__ __align__(16) char smem[131072];
    const int bid = blockIdx.x;                       // [0, 768)
    const int wg = (bid & 7) * 96 + (bid >> 3);
    const int nc = wg % 6, mc = wg / 6;
    if (nc < 4) {
        gemm_body256<0, 1, 0, 0>(smem, mc * 256, nc * 256,
            bufA, nullptr, we2w, be2, nullptr, bufB, 512, 1024, 512, 1024, 0, 0);
    } else {
        gemm_body256<0, 1, 0, 1>(smem, mc * 256, (nc - 4) * 256,
            bufA, (const u16*)bufA + 512, wcomb2, bconst, nullptr, bufC,
            512, 1024, 512, 512, 1024, 1 << 30);
    }
}

// ---------------------------------------------------------------------------
// khot + kfinal fused (R1/R7-proven): wave-per-row, 2x8-bit radix with
// 8 per-lane-group sub-histograms (264-stride bank skew).
// ---------------------------------------------------------------------------
#define KH_GS 264

__device__ inline void suffix_pick(const unsigned* h, int lane, unsigned target,
                                   unsigned& bucket, unsigned& rem)
{
    uint4 hv = make_uint4(0u, 0u, 0u, 0u);
#pragma unroll
    for (int g = 0; g < 8; g++) {
        uint4 t = *(const uint4*)(h + g * KH_GS + lane * 4);
        hv.x += t.x; hv.y += t.y; hv.z += t.z; hv.w += t.w;
    }
    unsigned local = hv.x + hv.y + hv.z + hv.w;
    unsigned incl = local;
#pragma unroll
    for (int off = 1; off < 64; off <<= 1) {
        unsigned t = __shfl_down(incl, off);
        if (lane + off < 64) incl += t;
    }
    unsigned higher = incl - local;
    unsigned s3 = higher + hv.w;
    unsigned s2 = s3 + hv.z;
    unsigned s1 = s2 + hv.y;
    unsigned s0 = s1 + hv.x;
    unsigned suf[5] = {s0, s1, s2, s3, higher};
    int bj = -1; unsigned rm = 0;
#pragma unroll
    for (int j = 0; j < 4; j++)
        if (suf[j] >= target && suf[j + 1] < target) { bj = j; rm = target - suf[j + 1]; }
    unsigned long long mk = __ballot(bj >= 0);
    int src = (int)__ffsll((unsigned long long)mk) - 1;
    bucket = __shfl((unsigned)(lane * 4 + bj), src);
    rem    = __shfl(rm, src);
}

__device__ inline void hist_zero(unsigned* h, int lane) {
    uint4* h4 = (uint4*)h;                 // 8*264 u32 = 528 uint4
#pragma unroll
    for (int i = 0; i < 8; i++) h4[lane + i * 64] = make_uint4(0u, 0u, 0u, 0u);
    if (lane < 16) h4[512 + lane] = make_uint4(0u, 0u, 0u, 0u);
}

__global__ __launch_bounds__(256) void khot_kernel(
    u16* __restrict__ lb, const float* __restrict__ kpart,
    const float* __restrict__ b3, const float* __restrict__ kscale,
    float* __restrict__ mf, float* __restrict__ kout, float* __restrict__ scl)
{
    __shared__ unsigned hist[4][8 * KH_GS];   // 4 waves x 8.25 KB = 33 KB
    const int w = threadIdx.x >> 6, lane = threadIdx.x & 63;
    const int row = blockIdx.x * 4 + w;
    u16* rp = lb + (size_t)row * QDIM;
    float* mfp = mf + (size_t)row * QDIM;

    float z = kpart[row] + b3[0];
    float kk = 1024.0f / (1.0f + expf(-z));
    float sc = 1.0f / (1.0f + expf(-kscale[0]));
    float kvv = fminf(fmaxf(kk * sc * 2.0f, 1.0f), 1024.0f);
    if (lane == 0) kout[row] = kvv;
    if (row == 0 && lane == 0) scl[0] = 0.0f;

    u16x8 v0 = *(const u16x8*)(rp + lane * 8);
    u16x8 v1 = *(const u16x8*)(rp + 512 + lane * 8);
    unsigned key[2][8];
#pragma unroll
    for (int j = 0; j < 8; j++) {
        unsigned a = v0[j], b = v1[j];
        key[0][j] = (a & 0x8000u) ? (~a & 0xffffu) : (a | 0x8000u);
        key[1][j] = (b & 0x8000u) ? (~b & 0xffffu) : (b | 0x8000u);
    }
    int mi = (int)ceilf(kvv);
    mi = mi < 1 ? 1 : (mi > QDIM ? QDIM : mi);
    const unsigned m = (unsigned)mi;
    unsigned* h = hist[w];
    unsigned* hg = h + (lane >> 3) * KH_GS;   // this lane's sub-histogram

    hist_zero(h, lane);
    __threadfence_block();
#pragma unroll
    for (int c = 0; c < 2; c++)
#pragma unroll
        for (int j = 0; j < 8; j++)
            atomicAdd(&hg[key[c][j] >> 8], 1u);
    __threadfence_block();
    unsigned hi, rem1;
    suffix_pick(h, lane, m, hi, rem1);

    hist_zero(h, lane);
    __threadfence_block();
#pragma unroll
    for (int c = 0; c < 2; c++)
#pragma unroll
        for (int j = 0; j < 8; j++)
            if ((key[c][j] >> 8) == hi) atomicAdd(&hg[key[c][j] & 255u], 1u);
    __threadfence_block();
    unsigned lo, need;
    suffix_pick(h, lane, rem1, lo, need);

    const unsigned um = (hi << 8) | lo;

    unsigned cnt0 = 0, cnt1 = 0;
#pragma unroll
    for (int j = 0; j < 8; j++) { cnt0 += (key[0][j] == um); cnt1 += (key[1][j] == um); }
    unsigned pack = cnt0 | (cnt1 << 16);
    unsigned incl = pack;
#pragma unroll
    for (int off = 1; off < 64; off <<= 1) {
        unsigned t = __shfl_up(incl, off);
        if (lane >= off) incl += t;
    }
    unsigned excl = incl - pack;
    unsigned tot0 = __shfl(incl, 63) & 0xffffu;
    unsigned r0 = excl & 0xffffu;
    unsigned r1 = tot0 + (excl >> 16);

    float of[2][8];
    u16x8 mb0, mb1;
#pragma unroll
    for (int j = 0; j < 8; j++) {
        unsigned kv_ = key[0][j];
        bool s;
        if (kv_ > um) s = true;
        else if (kv_ == um) { s = (r0 < need); r0++; }
        else s = false;
        of[0][j] = s ? 1.0f : 0.0f;
        mb0[j] = s ? (u16)0x3F80 : (u16)0;
    }
#pragma unroll
    for (int j = 0; j < 8; j++) {
        unsigned kv_ = key[1][j];
        bool s;
        if (kv_ > um) s = true;
        else if (kv_ == um) { s = (r1 < need); r1++; }
        else s = false;
        of[1][j] = s ? 1.0f : 0.0f;
        mb1[j] = s ? (u16)0x3F80 : (u16)0;
    }
    *(float4*)(mfp + lane * 8)           = make_float4(of[0][0], of[0][1], of[0][2], of[0][3]);
    *(float4*)(mfp + lane * 8 + 4)       = make_float4(of[0][4], of[0][5], of[0][6], of[0][7]);
    *(float4*)(mfp + 512 + lane * 8)     = make_float4(of[1][0], of[1][1], of[1][2], of[1][3]);
    *(float4*)(mfp + 512 + lane * 8 + 4) = make_float4(of[1][4], of[1][5], of[1][6], of[1][7]);
    *(u16x8*)(rp + lane * 8)       = mb0;
    *(u16x8*)(rp + 512 + lane * 8) = mb1;
}

// ---------------------------------------------------------------------------
extern "C" void kernel_launch(void* const* d_in, const int* in_sizes, int n_in,
                              void* d_out, int out_size, void* d_ws, size_t ws_size,
                              hipStream_t stream) {
    const float* x     = (const float*)d_in[0];
    const float* W_e1  = (const float*)d_in[1];
    const float* b_e1  = (const float*)d_in[2];
    const float* W_e2  = (const float*)d_in[3];
    const float* b_e2  = (const float*)d_in[4];
    const float* W_cb  = (const float*)d_in[5];
    const float* W_d1  = (const float*)d_in[6];
    const float* b_d1  = (const float*)d_in[7];
    const float* W_d2  = (const float*)d_in[8];
    const float* b_d2  = (const float*)d_in[9];
    const float* W_k1  = (const float*)d_in[10];
    const float* b_k1  = (const float*)d_in[11];
    const float* W_k2  = (const float*)d_in[12];
    const float* b_k2  = (const float*)d_in[13];
    const float* W_k3  = (const float*)d_in[14];
    const float* b_k3  = (const float*)d_in[15];
    const float* k_scl = (const float*)d_in[16];

    float* out   = (float*)d_out;
    float* recon = out;
    float* maskf = out + OUT_KHOT_OFF;
    float* scl   = out + OUT_SCALAR_OFF;
    float* kout  = out + OUT_K_OFF;

    char* ws = (char*)d_ws;
    bf16* wb_k1  = (bf16*)(ws + WS_WK1);
    bf16* wb_e2  = (bf16*)(ws + WS_WE2);
    bf16* wb_cb  = (bf16*)(ws + WS_WCB);
    bf16* wb_d1  = (bf16*)(ws + WS_WD1);
    bf16* wb_d2  = (bf16*)(ws + WS_WD2);
    bf16* wb_k2  = (bf16*)(ws + WS_WK2);
    bf16* wstk   = (bf16*)(ws + WS_WSTK);
    float* bstk  = (float*)(ws + WS_BSTK);
    float* kpart = (float*)(ws + WS_KPART);
    bf16* bufA   = (bf16*)(ws + WS_BUFA);
    bf16* bufB   = (bf16*)(ws + WS_BUFB);
    bf16* bufC   = (bf16*)(ws + WS_BUFC);
    bf16* bufX   = (bf16*)(ws + WS_BUFX);
    bf16* we2t   = (bf16*)(ws + WS_WE2T);
    bf16* wcomb2 = (bf16*)(ws + WS_WCOMB2);
    float* bconst = (float*)(ws + WS_BCONST);

    const dim3 blk(256);
    const dim3 blk512(512);
    const int FULL = 1 << 30;

    // prep: conversions (incl. x->bf16) + stacked W/b + We2T + bconst + kpart
    cvt_kernel<<<dim3(CVT_GRID), blk, 0, stream>>>(
        W_e1, W_e2, W_cb, W_d1, W_d2, W_k1, W_k2, b_e1, b_e2, b_k1, x, ws);

    // Wcomb2 (16 blocks, overlapped under E1) + E1||K1a (2048, swizzled)
    fusedA_kernel<<<dim3(2064), blk, 0, stream>>>(
        bufX, wstk, bstk, bufA, wb_k1 + 256, we2t, wcomb2);

    // E2 + K1b' merged (256² pipelined, 768 blocks)
    fusedB_kernel<<<dim3(768), blk512, 0, stream>>>(
        bufA, wb_e2, b_e2, bufB, wcomb2, bconst, bufC);

    // K2+kdot: kpart[row] += relu(hk1 @ Wk2^T + b_k2) . w3  (128², 1024 blk)
    mgemm<2, 1, 0, 0, 4><<<dim3(1024), blk, 0, stream>>>(
        bufC, nullptr, wb_k2, b_k2, W_k3, kpart, 512, 512, 512, 512, 0, FULL);

    // khot (+kfinal): logits -> fp32 mask (d_out) + bf16 mask; k -> kout/scl
    khot_kernel<<<dim3(Bn / 4), blk, 0, stream>>>(
        (u16*)bufB, kpart, b_k3, k_scl, maskf, kout, scl);

    // CB: q = (mask/k) @ Wcb^T -> bufA (128², 512 blocks)
    mgemm<0, 0, 1, 0, 2><<<dim3(512), blk, 0, stream>>>(
        bufB, nullptr, wb_cb, nullptr, kout, bufA, 1024, 1024, 1024, 256, 0, 0);

    // D1: hd1 = relu(q @ Wd1^T + b_d1) -> bufC (128², 1024 blocks)
    mgemm<0, 1, 0, 0, 4><<<dim3(1024), blk, 0, stream>>>(
        bufA, nullptr, wb_d1, b_d1, nullptr, bufC, 256, 256, 256, 512, 0, FULL);

    // D2: recon = hd1 @ Wd2^T + b_d2 -> d_out (fp32) (128², 512 blocks)
    mgemm<1, 1, 0, 0, 2><<<dim3(512), blk, 0, stream>>>(
        bufC, nullptr, wb_d2, b_d2, nullptr, recon, 512, 512, 512, 256, 0, 0);
}

// Round 12
// 439.367 us; speedup vs baseline: 1.2966x; 1.0246x over previous
//
#include <hip/hip_runtime.h>
#include <hip/hip_bf16.h>
#include <math.h>

typedef __hip_bfloat16 bf16;
typedef unsigned short u16;
using frag8 = __attribute__((ext_vector_type(8))) short;   // 8 bf16 = 4 VGPRs
using f32x4 = __attribute__((ext_vector_type(4))) float;   // MFMA accumulator
using u16x8 = __attribute__((ext_vector_type(8))) unsigned short;

// Problem constants
#define Bn      32768
#define IN_DIM  256
#define N_HDIM  512
#define QDIM    1024
#define N_EMBD  256

// Output layout (float32): recon [B*256] | khot [B*1024] | scalar [1] | k [B]
#define OUT_KHOT_OFF   ((size_t)Bn * IN_DIM)
#define OUT_SCALAR_OFF (OUT_KHOT_OFF + (size_t)Bn * QDIM)
#define OUT_K_OFF      (OUT_SCALAR_OFF + 1)

// Workspace layout (bytes)
#define WS_WK1    0                                   // 512x1280 bf16 (full)
#define WS_WE2    (WS_WK1 + 512*1280*2)               // 1024x512
#define WS_WCB    (WS_WE2 + 1024*512*2)               // 256x1024
#define WS_WD1    (WS_WCB + 256*1024*2)               // 512x256
#define WS_WD2    (WS_WD1 + 512*256*2)                // 256x512
#define WS_WK2    (WS_WD2 + 256*512*2)                // 512x512
#define WS_WSTK   (WS_WK2 + 512*512*2)                // 1024x256 [We1 ; Wk1[:,:256]]
#define WS_BSTK   (WS_WSTK + 1024*256*2)              // 1024 fp32 [b_e1 | 0]
#define WS_KPART  (WS_BSTK + 1024*4)                  // Bn fp32 (zeroed by cvt)
#define WS_BUFA   (WS_KPART + (size_t)Bn*4)           // Bn x 1024 bf16: [h1|kp1]
#define WS_BUFB   (WS_BUFA + (size_t)Bn*1024*2)       // Bn x 1024 bf16: logits -> mask
#define WS_BUFC   (WS_BUFB + (size_t)Bn*1024*2)       // Bn x 512 bf16: xb -> hk1
#define WS_WE2T   (WS_BUFC + (size_t)Bn*512*2)        // 512x1024 bf16 (We2 transposed)
#define WS_WCOMB2 (WS_WE2T + 512*1024*2)              // 512x512 bf16 (Wk1b @ We2)
#define WS_BCONST (WS_WCOMB2 + 512*512*2)             // 512 fp32
// bf16 x (32768x256 = 16.8 MB) overlays bufC: written by cvt, read by E1
// (fusedA); fusedB overwrites the region with hk1 only AFTER E1 completes.
#define WS_BUFX   WS_BUFC

// cvt grid segmentation
#define CVT_BASE  2177
#define CVT_T     512
#define CVT_BC    128
#define CVT_KZ    32
#define CVT_X     4096
#define CVT_GRID  (CVT_BASE + CVT_T + CVT_BC + CVT_KZ + CVT_X)   // 6945

__device__ inline void async_copy16(const void* g, void* l) {
    __builtin_amdgcn_global_load_lds(
        (const __attribute__((address_space(1))) void*)g,
        (__attribute__((address_space(3))) void*)l, 16, 0, 0);
}

__device__ inline void cv4(bf16* d, float4 v) {
    union { short4 s; bf16 h[4]; } u;
    u.h[0] = __float2bfloat16(v.x); u.h[1] = __float2bfloat16(v.y);
    u.h[2] = __float2bfloat16(v.z); u.h[3] = __float2bfloat16(v.w);
    *(short4*)d = u.s;
}

// ---------------------------------------------------------------------------
// One-shot prep: all weight bf16 conversions, stacked [We1;Wk1a] + bias,
// We2 transpose, bconst = Wk1b . b_e2 + b_k1, kpart zeroing, x -> bf16.
// ---------------------------------------------------------------------------
__global__ __launch_bounds__(256) void cvt_kernel(
    const float* __restrict__ We1, const float* __restrict__ We2,
    const float* __restrict__ Wcb, const float* __restrict__ Wd1,
    const float* __restrict__ Wd2, const float* __restrict__ Wk1,
    const float* __restrict__ Wk2, const float* __restrict__ be1,
    const float* __restrict__ be2, const float* __restrict__ bk1,
    const float* __restrict__ x, char* __restrict__ ws)
{
    const int bx = blockIdx.x, tid = threadIdx.x;
    if (bx < CVT_BASE) {
        int id = bx * 256 + tid;
        const float* src; bf16* dst; int off;
        if      (id < 163840) { src = Wk1; dst = (bf16*)(ws + WS_WK1); off = id; }
        else if (id < 294912) { src = We2; dst = (bf16*)(ws + WS_WE2); off = id - 163840; }
        else if (id < 360448) { src = Wcb; dst = (bf16*)(ws + WS_WCB); off = id - 294912; }
        else if (id < 393216) { src = Wd1; dst = (bf16*)(ws + WS_WD1); off = id - 360448; }
        else if (id < 425984) { src = Wd2; dst = (bf16*)(ws + WS_WD2); off = id - 393216; }
        else if (id < 491520) { src = Wk2; dst = (bf16*)(ws + WS_WK2); off = id - 425984; }
        else if (id < 524288) { src = We1; dst = (bf16*)(ws + WS_WSTK); off = id - 491520; }
        else if (id < 557056) {           // Wk1[:, :256] -> wstk rows 512..1023
            int l = id - 524288; int r = l >> 6, c4 = (l & 63) * 4;
            float4 v = *(const float4*)(Wk1 + (size_t)r * 1280 + c4);
            cv4((bf16*)(ws + WS_WSTK) + 131072 + r * 256 + c4, v);
            return;
        } else {                           // bias_stk: [b_e1 | zeros], fp32
            int l = id - 557056;
            float4 v = (l < 128) ? *(const float4*)(be1 + l * 4)
                                 : make_float4(0.f, 0.f, 0.f, 0.f);
            *(float4*)((float*)(ws + WS_BSTK) + l * 4) = v;
            return;
        }
        float4 v = *(const float4*)(src + (size_t)off * 4);
        cv4(dst + (size_t)off * 4, v);
    } else if (bx < CVT_BASE + CVT_T) {
        int local = (bx - CVT_BASE) * 256 + tid;
        int n = local & 511;
        int k = (local >> 9) * 4;
        float4 v;
        v.x = We2[(size_t)(k + 0) * 512 + n];
        v.y = We2[(size_t)(k + 1) * 512 + n];
        v.z = We2[(size_t)(k + 2) * 512 + n];
        v.w = We2[(size_t)(k + 3) * 512 + n];
        cv4((bf16*)(ws + WS_WE2T) + (size_t)n * 1024 + k, v);
    } else if (bx < CVT_BASE + CVT_T + CVT_BC) {
        int r = (bx - CVT_BASE - CVT_T) * 4 + (tid >> 6);
        int lane = tid & 63;
        const float* wr = Wk1 + (size_t)r * 1280 + 256;
        float s = 0.f;
#pragma unroll
        for (int t = 0; t < 16; t++) {
            int j = lane + t * 64;
            s = fmaf(wr[j], be2[j], s);
        }
#pragma unroll
        for (int off = 32; off > 0; off >>= 1) s += __shfl_down(s, off);
        if (lane == 0) ((float*)(ws + WS_BCONST))[r] = s + bk1[r];
    } else if (bx < CVT_BASE + CVT_T + CVT_BC + CVT_KZ) {
        int idx = ((bx - CVT_BASE - CVT_T - CVT_BC) * 256 + tid) * 4;
        *(float4*)((float*)(ws + WS_KPART) + idx) = make_float4(0.f, 0.f, 0.f, 0.f);
    } else {
        // x (32768x256 fp32) -> bf16 bufX; 8 elems/thread, 16B stores
        int id = (bx - CVT_BASE - CVT_T - CVT_BC - CVT_KZ) * 256 + tid;
        const float* src = x + (size_t)id * 8;
        float4 v0 = *(const float4*)src;
        float4 v1 = *(const float4*)(src + 4);
        union { frag8 s; bf16 h[8]; } u;
        u.h[0] = __float2bfloat16(v0.x); u.h[1] = __float2bfloat16(v0.y);
        u.h[2] = __float2bfloat16(v0.z); u.h[3] = __float2bfloat16(v0.w);
        u.h[4] = __float2bfloat16(v1.x); u.h[5] = __float2bfloat16(v1.y);
        u.h[6] = __float2bfloat16(v1.z); u.h[7] = __float2bfloat16(v1.w);
        *(frag8*)((bf16*)(ws + WS_BUFX) + (size_t)id * 8) = u.s;
    }
}

// ---------------------------------------------------------------------------
// 128x128 2-barrier GEMM body (R7-proven: 4 waves, 32 KB LDS, 3 blocks/CU).
// OMODE: 0 = bf16 C (coalesced); 1 = fp32 C; 2 = kdot epilogue (atomicAdd).
// ---------------------------------------------------------------------------
template<int OMODE, int BIAS, int INVK, int ACCIN>
__device__ __forceinline__ void gemm_body(
    char* smem, int m0, int n0,
    const bf16* __restrict__ A, const u16* __restrict__ accin,
    const bf16* __restrict__ W, const float* __restrict__ bias,
    const float* __restrict__ kv, void* __restrict__ Cp,
    int K, int lda, int ldw, int ldc, int ldacc, int relu_ncols)
{
    bf16* sA = (bf16*)smem;               // 128 x 64 = 16 KB
    bf16* sB = (bf16*)(smem + 16384);     // 128 x 64 = 16 KB

    const int tid = threadIdx.x;
    const int wv = tid >> 6, ln = tid & 63;
    const int wr = wv >> 1, wc = wv & 1;
    const int lm = ln & 15, q = ln >> 4;

    f32x4 acc[4][4];
#pragma unroll
    for (int i = 0; i < 4; i++)
#pragma unroll
        for (int j = 0; j < 4; j++)
            acc[i][j] = (f32x4){0.f, 0.f, 0.f, 0.f};

    for (int k0 = 0; k0 < K; k0 += 64) {
#pragma unroll
        for (int i = 0; i < 4; i++) {
            int c = wv * 256 + i * 64 + ln;
            int row = c >> 3;
            int g = (c & 7) ^ (row & 7);
            async_copy16(A + (size_t)(m0 + row) * lda + k0 + g * 8, &sA[c * 8]);
        }
#pragma unroll
        for (int i = 0; i < 4; i++) {
            int c = wv * 256 + i * 64 + ln;
            int row = c >> 3;
            int g = (c & 7) ^ (row & 7);
            async_copy16(W + (size_t)(n0 + row) * ldw + k0 + g * 8, &sB[c * 8]);
        }
        __syncthreads();

#pragma unroll
        for (int kk = 0; kk < 2; kk++) {
            frag8 af[4], bfr[4];
#pragma unroll
            for (int t = 0; t < 4; t++) {
                int r = wr * 64 + t * 16 + lm;
                af[t] = *(const frag8*)&sA[r * 64 + (((kk * 4 + q) ^ (r & 7)) * 8)];
            }
#pragma unroll
            for (int t = 0; t < 4; t++) {
                int n = wc * 64 + t * 16 + lm;
                bfr[t] = *(const frag8*)&sB[n * 64 + (((kk * 4 + q) ^ (n & 7)) * 8)];
            }
#pragma unroll
            for (int mt = 0; mt < 4; mt++)
#pragma unroll
                for (int nt = 0; nt < 4; nt++)
                    acc[mt][nt] = __builtin_amdgcn_mfma_f32_16x16x32_bf16(
                        af[mt], bfr[nt], acc[mt][nt], 0, 0, 0);
        }
        __syncthreads();
    }

    if (OMODE == 2) {
        float* kpart = (float*)Cp;
#pragma unroll
        for (int mt = 0; mt < 4; mt++) {
#pragma unroll
            for (int r = 0; r < 4; r++) {
                int row = m0 + wr * 64 + mt * 16 + q * 4 + r;
                float s = 0.f;
#pragma unroll
                for (int nt = 0; nt < 4; nt++) {
                    int col = n0 + wc * 64 + nt * 16 + lm;
                    float v = acc[mt][nt][r] + bias[col];
                    v = fmaxf(v, 0.f);
                    s = fmaf(v, kv[col], s);
                }
#pragma unroll
                for (int off = 8; off > 0; off >>= 1) s += __shfl_down(s, off);
                if (lm == 0) atomicAdd(&kpart[row], s);
            }
        }
    } else if (OMODE == 1) {
#pragma unroll
        for (int mt = 0; mt < 4; mt++) {
#pragma unroll
            for (int r = 0; r < 4; r++) {
                int row = m0 + wr * 64 + mt * 16 + q * 4 + r;
#pragma unroll
                for (int nt = 0; nt < 4; nt++) {
                    int col = n0 + wc * 64 + nt * 16 + lm;
                    float v = acc[mt][nt][r];
                    if (BIAS) v += bias[col];
                    if (col < relu_ncols) v = fmaxf(v, 0.f);
                    ((float*)Cp)[(size_t)row * ldc + col] = v;
                }
            }
        }
    } else {
        u16* st = (u16*)smem;   // 128 x 128 bf16 = 32 KB (post-barrier overlay)
#pragma unroll
        for (int mt = 0; mt < 4; mt++) {
#pragma unroll
            for (int r = 0; r < 4; r++) {
                int rl = wr * 64 + mt * 16 + q * 4 + r;
                int rg = m0 + rl;
                float scale = 1.0f;
                if (INVK) scale = 1.0f / kv[rg];
#pragma unroll
                for (int nt = 0; nt < 4; nt++) {
                    int cl = wc * 64 + nt * 16 + lm;
                    int cg = n0 + cl;
                    float v = acc[mt][nt][r];
                    if (BIAS) v += bias[cg];
                    if (ACCIN) {
                        u16 raw = accin[(size_t)rg * ldacc + cg];
                        union { u16 u; bf16 h; } cu; cu.u = raw;
                        v += __bfloat162float(cu.h);
                    }
                    if (INVK) v *= scale;
                    if (cg < relu_ncols) v = fmaxf(v, 0.f);
                    union { u16 u; bf16 h; } ou; ou.h = __float2bfloat16(v);
                    st[rl * 128 + cl] = ou.u;
                }
            }
        }
        __syncthreads();
        u16* Cb = (u16*)Cp;
#pragma unroll
        for (int c = 0; c < 8; c++) {
            int idx = tid + c * 256;              // 0..2047 chunks of 8 bf16
            int rl = idx >> 4, cl = (idx & 15) * 8;
            *(uint4*)(Cb + (size_t)(m0 + rl) * ldc + n0 + cl) = ((const uint4*)st)[idx];
        }
    }
}

template<int OMODE, int BIAS, int INVK, int ACCIN, int NCH>
__global__ __launch_bounds__(256, 3) void mgemm(
    const bf16* __restrict__ Ap, const u16* __restrict__ accin,
    const bf16* __restrict__ W, const float* __restrict__ bias,
    const float* __restrict__ kv, void* __restrict__ Cp,
    int K, int lda, int ldw, int ldc, int ldacc, int relu_ncols)
{
    __shared__ __align__(16) char smem[32768];
    const int bid = blockIdx.x;
    const int cpx = gridDim.x >> 3;
    const int wg = (bid & 7) * cpx + (bid >> 3);
    const int nc = wg % NCH, mc = wg / NCH;
    gemm_body<OMODE, BIAS, INVK, ACCIN>(
        smem, mc * 128, nc * 128,
        Ap, accin, W, bias, kv, Cp, K, lda, ldw, ldc, ldacc, relu_ncols);
}

// fusedA (R7-proven): bid<16 -> Wcomb2 = Wk1b @ We2 (first, hides under E1);
// bid>=16 -> E1||K1a over bf16 x (K=256), XCD-chunked swizzle.
__global__ __launch_bounds__(256, 3) void fusedA_kernel(
    const bf16* __restrict__ xb, const bf16* __restrict__ wstk,
    const float* __restrict__ bstk, bf16* __restrict__ bufA,
    const bf16* __restrict__ wk1b, const bf16* __restrict__ we2t,
    bf16* __restrict__ wcomb2)
{
    __shared__ __align__(16) char smem[32768];
    const int bid = blockIdx.x;
    if (bid < 16) {
        gemm_body<0, 0, 0, 0>(smem, (bid & 3) * 128, (bid >> 2) * 128,
            wk1b, nullptr, we2t, nullptr, nullptr, wcomb2, 1024, 1280, 1024, 512, 0, 0);
    } else {
        const int b = bid - 16;                       // [0, 2048)
        const int wg = (b & 7) * 256 + (b >> 3);
        const int mc = wg >> 3, nc = wg & 7;
        gemm_body<0, 1, 0, 0>(smem, mc * 128, nc * 128,
            xb, nullptr, wstk, bstk, nullptr, bufA, 256, 256, 256, 1024, 0, 512);
    }
}

// fusedB (R7-proven): c in [0,12): c<8 -> E2 n-chunk c; c>=8 -> K1b' c-8.
__global__ __launch_bounds__(256, 3) void fusedB_kernel(
    const bf16* __restrict__ bufA, const bf16* __restrict__ we2w,
    const float* __restrict__ be2, bf16* __restrict__ bufB,
    const bf16* __restrict__ wcomb2, const float* __restrict__ bconst,
    bf16* __restrict__ bufC)
{
    __shared__ __align__(16) char smem[32768];
    const int bid = blockIdx.x;                       // [0, 3072)
    const int wg = (bid & 7) * 384 + (bid >> 3);
    const int nc = wg % 12, mc = wg / 12;
    if (nc < 8) {
        gemm_body<0, 1, 0, 0>(smem, mc * 128, nc * 128,
            bufA, nullptr, we2w, be2, nullptr, bufB, 512, 1024, 512, 1024, 0, 0);
    } else {
        gemm_body<0, 1, 0, 1>(smem, mc * 128, (nc - 8) * 128,
            bufA, (const u16*)bufA + 512, wcomb2, bconst, nullptr, bufC,
            512, 1024, 512, 512, 1024, 1 << 30);
    }
}

// ---------------------------------------------------------------------------
// FUSED DECODER: one kernel = CB (q = mask/k @ Wcb^T) -> D1 (hd1 = relu(q@
// Wd1^T+b)) -> D2 (recon = hd1@Wd2^T+b). Grid = 256 blocks (1/CU, zero tail),
// 512 thr (8 waves 4Mx2N). q and hd1 NEVER leave LDS: kills their global
// round-trips (~185 MB staged traffic) + 2 launch tails.
// LDS 128 KB (proven size): [0,64K) phase region (CB dbuf staging; then
// hd1-quarter 32K + W-staging 32K), [64K,128K) Q = q 128x256 bf16 as 4
// XOR-swizzled 64-col k-tiles (16 KB each) matching the frag-read layout.
// CB uses the R10-proven counted-vmcnt pipeline (16 K-tiles deep). D1/D2
// read A from LDS (no global A); only small L2-resident W tiles stream.
// ---------------------------------------------------------------------------
__global__ __launch_bounds__(512, 2) void decoder_kernel(
    const bf16* __restrict__ mask, const bf16* __restrict__ wcb,
    const float* __restrict__ kv, const bf16* __restrict__ wd1,
    const float* __restrict__ bd1, const bf16* __restrict__ wd2,
    const float* __restrict__ bd2, float* __restrict__ recon)
{
    __shared__ __align__(16) char smem[131072];
    u16* Q = (u16*)(smem + 65536);        // 4 k-tiles x [128][64] bf16
    const int tid = threadIdx.x;
    const int wv = tid >> 6, ln = tid & 63;
    const int wr = wv >> 1, wc = wv & 1;  // 4 M-waves x 2 N-waves
    const int lm = ln & 15, q = ln >> 4;
    const int m0 = blockIdx.x * 128;

    f32x4 racc[2][8];                     // persistent recon acc (wave 32x128)
#pragma unroll
    for (int i = 0; i < 2; i++)
#pragma unroll
        for (int j = 0; j < 8; j++)
            racc[i][j] = (f32x4){0.f, 0.f, 0.f, 0.f};

    // ==== CB phase: two 128-col passes, pipelined (16 k-tiles, vmcnt(4)) ====
#pragma unroll 1
    for (int p = 0; p < 2; p++) {
        f32x4 acc[2][4];
#pragma unroll
        for (int i = 0; i < 2; i++)
#pragma unroll
            for (int j = 0; j < 4; j++)
                acc[i][j] = (f32x4){0.f, 0.f, 0.f, 0.f};
        const bf16* Wp = wcb + (size_t)(p * 128) * 1024;

        auto stage = [&](int t, int b) {
            bf16* sA = (bf16*)(smem + b * 32768);          // 128x64 mask tile
            bf16* sB = (bf16*)(smem + b * 32768 + 16384);  // 128x64 Wcb tile
            const int k0 = t * 64;
#pragma unroll
            for (int i = 0; i < 2; i++) {
                int c = i * 512 + tid;
                int row = c >> 3, g = (c & 7) ^ (row & 7);
                async_copy16(mask + (size_t)(m0 + row) * 1024 + k0 + g * 8, &sA[c * 8]);
            }
#pragma unroll
            for (int i = 0; i < 2; i++) {
                int c = i * 512 + tid;
                int row = c >> 3, g = (c & 7) ^ (row & 7);
                async_copy16(Wp + (size_t)row * 1024 + k0 + g * 8, &sB[c * 8]);
            }
        };
        asm volatile("s_waitcnt vmcnt(0)" ::: "memory");
        __syncthreads();                   // staging region free for reuse
        stage(0, 0);
        stage(1, 1);
        int cur = 0;
        for (int t = 0; t < 16; t++) {
            if (t + 1 < 16) { asm volatile("s_waitcnt vmcnt(4)" ::: "memory"); }
            else            { asm volatile("s_waitcnt vmcnt(0)" ::: "memory"); }
            __builtin_amdgcn_s_barrier();
            __builtin_amdgcn_sched_barrier(0);
            bf16* sA = (bf16*)(smem + cur * 32768);
            bf16* sB = (bf16*)(smem + cur * 32768 + 16384);
#pragma unroll
            for (int kk = 0; kk < 2; kk++) {
                frag8 af[2], bfr[4];
#pragma unroll
                for (int tt = 0; tt < 2; tt++) {
                    int r = wr * 32 + tt * 16 + lm;
                    af[tt] = *(const frag8*)&sA[r * 64 + (((kk * 4 + q) ^ (r & 7)) * 8)];
                }
#pragma unroll
                for (int tt = 0; tt < 4; tt++) {
                    int n = wc * 64 + tt * 16 + lm;
                    bfr[tt] = *(const frag8*)&sB[n * 64 + (((kk * 4 + q) ^ (n & 7)) * 8)];
                }
                __builtin_amdgcn_s_setprio(1);
#pragma unroll
                for (int mt = 0; mt < 2; mt++)
#pragma unroll
                    for (int nt = 0; nt < 4; nt++)
                        acc[mt][nt] = __builtin_amdgcn_mfma_f32_16x16x32_bf16(
                            af[mt], bfr[nt], acc[mt][nt], 0, 0, 0);
                __builtin_amdgcn_s_setprio(0);
            }
            __builtin_amdgcn_sched_barrier(0);
            __builtin_amdgcn_s_barrier();
            __builtin_amdgcn_sched_barrier(0);
            if (t + 2 < 16) stage(t + 2, cur);
            cur ^= 1;
        }
        // epilogue: q = acc / k[row]  -> Q (swizzled, 64-col k-tiles)
#pragma unroll
        for (int mt = 0; mt < 2; mt++) {
#pragma unroll
            for (int r = 0; r < 4; r++) {
                int row_l = wr * 32 + mt * 16 + q * 4 + r;
                float scale = 1.0f / kv[m0 + row_l];
#pragma unroll
                for (int nt = 0; nt < 4; nt++) {
                    int cg = p * 128 + wc * 64 + nt * 16 + lm;
                    int kt = cg >> 6, c64 = cg & 63;
                    union { u16 u; bf16 h; } ou;
                    ou.h = __float2bfloat16(acc[mt][nt][r] * scale);
                    Q[kt * 8192 + row_l * 64 + (((c64 >> 3) ^ (row_l & 7)) * 8) + (c64 & 7)] = ou.u;
                }
            }
        }
    }
    __syncthreads();                       // Q complete, staging region free

    // ==== D1/D2 quarters: hd1 128-col quarter -> recon accumulation ====
    u16* H = (u16*)smem;                   // hd1 quarter: 2 k-tiles x [128][64]
    bf16* WS = (bf16*)(smem + 32768);      // W staging (32 KB)
#pragma unroll 1
    for (int qt = 0; qt < 4; qt++) {
        // ---- D1: hd1q[128][128] = relu(Q @ Wd1[qt*128..]^T + bd1) ----
        f32x4 dacc[2][4];
#pragma unroll
        for (int i = 0; i < 2; i++)
#pragma unroll
            for (int j = 0; j < 4; j++)
                dacc[i][j] = (f32x4){0.f, 0.f, 0.f, 0.f};
        const bf16* W1 = wd1 + (size_t)(qt * 128) * 256;

        auto stg1 = [&](int t, int b) {
            bf16* sB = WS + b * 8192;      // 128x64 Wd1 tile (16 KB)
            const int k0 = t * 64;
#pragma unroll
            for (int i = 0; i < 2; i++) {
                int c = i * 512 + tid;
                int row = c >> 3, g = (c & 7) ^ (row & 7);
                async_copy16(W1 + (size_t)row * 256 + k0 + g * 8, &sB[c * 8]);
            }
        };
        asm volatile("s_waitcnt vmcnt(0)" ::: "memory");
        __syncthreads();                   // WS + H free
        stg1(0, 0);
        stg1(1, 1);
        int cur = 0;
        for (int t = 0; t < 4; t++) {
            if (t + 1 < 4) { asm volatile("s_waitcnt vmcnt(2)" ::: "memory"); }
            else           { asm volatile("s_waitcnt vmcnt(0)" ::: "memory"); }
            __builtin_amdgcn_s_barrier();
            __builtin_amdgcn_sched_barrier(0);
            bf16* sB = WS + cur * 8192;
#pragma unroll
            for (int kk = 0; kk < 2; kk++) {
                frag8 af[2], bfr[4];
#pragma unroll
                for (int tt = 0; tt < 2; tt++) {
                    int r = wr * 32 + tt * 16 + lm;
                    af[tt] = *(const frag8*)&Q[t * 8192 + r * 64 + (((kk * 4 + q) ^ (r & 7)) * 8)];
                }
#pragma unroll
                for (int tt = 0; tt < 4; tt++) {
                    int n = wc * 64 + tt * 16 + lm;
                    bfr[tt] = *(const frag8*)&sB[n * 64 + (((kk * 4 + q) ^ (n & 7)) * 8)];
                }
                __builtin_amdgcn_s_setprio(1);
#pragma unroll
                for (int mt = 0; mt < 2; mt++)
#pragma unroll
                    for (int nt = 0; nt < 4; nt++)
                        dacc[mt][nt] = __builtin_amdgcn_mfma_f32_16x16x32_bf16(
                            af[mt], bfr[nt], dacc[mt][nt], 0, 0, 0);
                __builtin_amdgcn_s_setprio(0);
            }
            __builtin_amdgcn_sched_barrier(0);
            __builtin_amdgcn_s_barrier();
            __builtin_amdgcn_sched_barrier(0);
            if (t + 2 < 4) stg1(t + 2, cur);
            cur ^= 1;
        }
        // D1 epilogue: relu(dacc + bd1) -> H (swizzled, 2 k-tiles of 64)
#pragma unroll
        for (int mt = 0; mt < 2; mt++) {
#pragma unroll
            for (int r = 0; r < 4; r++) {
                int row_l = wr * 32 + mt * 16 + q * 4 + r;
#pragma unroll
                for (int nt = 0; nt < 4; nt++) {
                    int col_l = wc * 64 + nt * 16 + lm;
                    float v = dacc[mt][nt][r] + bd1[qt * 128 + col_l];
                    v = fmaxf(v, 0.f);
                    int kt = col_l >> 6, c64 = col_l & 63;
                    union { u16 u; bf16 h; } ou; ou.h = __float2bfloat16(v);
                    H[kt * 8192 + row_l * 64 + (((c64 >> 3) ^ (row_l & 7)) * 8) + (c64 & 7)] = ou.u;
                }
            }
        }
        __syncthreads();                   // H ready; WS free

        // ---- D2: racc += hd1q(LDS) @ Wd2[:, qt*128..]^T (2 k-steps) ----
#pragma unroll 1
        for (int kt2 = 0; kt2 < 2; kt2++) {
            const int k0 = qt * 128 + kt2 * 64;
#pragma unroll
            for (int i = 0; i < 4; i++) {  // stage Wd2 256x64 (32 KB) into WS
                int c = i * 512 + tid;
                int row = c >> 3, g = (c & 7) ^ (row & 7);
                async_copy16(wd2 + (size_t)row * 512 + k0 + g * 8, &WS[c * 8]);
            }
            asm volatile("s_waitcnt vmcnt(0)" ::: "memory");
            __syncthreads();
#pragma unroll
            for (int kk = 0; kk < 2; kk++) {
                frag8 af[2], bfr[8];
#pragma unroll
                for (int tt = 0; tt < 2; tt++) {
                    int r = wr * 32 + tt * 16 + lm;
                    af[tt] = *(const frag8*)&H[kt2 * 8192 + r * 64 + (((kk * 4 + q) ^ (r & 7)) * 8)];
                }
#pragma unroll
                for (int tt = 0; tt < 8; tt++) {
                    int n = wc * 128 + tt * 16 + lm;
                    bfr[tt] = *(const frag8*)&WS[n * 64 + (((kk * 4 + q) ^ (n & 7)) * 8)];
                }
                __builtin_amdgcn_s_setprio(1);
#pragma unroll
                for (int mt = 0; mt < 2; mt++)
#pragma unroll
                    for (int nt = 0; nt < 8; nt++)
                        racc[mt][nt] = __builtin_amdgcn_mfma_f32_16x16x32_bf16(
                            af[mt], bfr[nt], racc[mt][nt], 0, 0, 0);
                __builtin_amdgcn_s_setprio(0);
            }
            __syncthreads();               // WS reused next kt2 / next qt
        }
    }

    // ==== recon epilogue: fp32 direct ====
#pragma unroll
    for (int mt = 0; mt < 2; mt++) {
#pragma unroll
        for (int r = 0; r < 4; r++) {
            int row = m0 + wr * 32 + mt * 16 + q * 4 + r;
#pragma unroll
            for (int nt = 0; nt < 8; nt++) {
                int col = wc * 128 + nt * 16 + lm;
                recon[(size_t)row * 256 + col] = racc[mt][nt][r] + bd2[col];
            }
        }
    }
}

// ---------------------------------------------------------------------------
// khot + kfinal fused (R1/R7-proven): wave-per-row, 2x8-bit radix with
// 8 per-lane-group sub-histograms (264-stride bank skew).
// ---------------------------------------------------------------------------
#define KH_GS 264

__device__ inline void suffix_pick(const unsigned* h, int lane, unsigned target,
                                   unsigned& bucket, unsigned& rem)
{
    uint4 hv = make_uint4(0u, 0u, 0u, 0u);
#pragma unroll
    for (int g = 0; g < 8; g++) {
        uint4 t = *(const uint4*)(h + g * KH_GS + lane * 4);
        hv.x += t.x; hv.y += t.y; hv.z += t.z; hv.w += t.w;
    }
    unsigned local = hv.x + hv.y + hv.z + hv.w;
    unsigned incl = local;
#pragma unroll
    for (int off = 1; off < 64; off <<= 1) {
        unsigned t = __shfl_down(incl, off);
        if (lane + off < 64) incl += t;
    }
    unsigned higher = incl - local;
    unsigned s3 = higher + hv.w;
    unsigned s2 = s3 + hv.z;
    unsigned s1 = s2 + hv.y;
    unsigned s0 = s1 + hv.x;
    unsigned suf[5] = {s0, s1, s2, s3, higher};
    int bj = -1; unsigned rm = 0;
#pragma unroll
    for (int j = 0; j < 4; j++)
        if (suf[j] >= target && suf[j + 1] < target) { bj = j; rm = target - suf[j + 1]; }
    unsigned long long mk = __ballot(bj >= 0);
    int src = (int)__ffsll((unsigned long long)mk) - 1;
    bucket = __shfl((unsigned)(lane * 4 + bj), src);
    rem    = __shfl(rm, src);
}

__device__ inline void hist_zero(unsigned* h, int lane) {
    uint4* h4 = (uint4*)h;                 // 8*264 u32 = 528 uint4
#pragma unroll
    for (int i = 0; i < 8; i++) h4[lane + i * 64] = make_uint4(0u, 0u, 0u, 0u);
    if (lane < 16) h4[512 + lane] = make_uint4(0u, 0u, 0u, 0u);
}

__global__ __launch_bounds__(256) void khot_kernel(
    u16* __restrict__ lb, const float* __restrict__ kpart,
    const float* __restrict__ b3, const float* __restrict__ kscale,
    float* __restrict__ mf, float* __restrict__ kout, float* __restrict__ scl)
{
    __shared__ unsigned hist[4][8 * KH_GS];   // 4 waves x 8.25 KB = 33 KB
    const int w = threadIdx.x >> 6, lane = threadIdx.x & 63;
    const int row = blockIdx.x * 4 + w;
    u16* rp = lb + (size_t)row * QDIM;
    float* mfp = mf + (size_t)row * QDIM;

    float z = kpart[row] + b3[0];
    float kk = 1024.0f / (1.0f + expf(-z));
    float sc = 1.0f / (1.0f + expf(-kscale[0]));
    float kvv = fminf(fmaxf(kk * sc * 2.0f, 1.0f), 1024.0f);
    if (lane == 0) kout[row] = kvv;
    if (row == 0 && lane == 0) scl[0] = 0.0f;

    u16x8 v0 = *(const u16x8*)(rp + lane * 8);
    u16x8 v1 = *(const u16x8*)(rp + 512 + lane * 8);
    unsigned key[2][8];
#pragma unroll
    for (int j = 0; j < 8; j++) {
        unsigned a = v0[j], b = v1[j];
        key[0][j] = (a & 0x8000u) ? (~a & 0xffffu) : (a | 0x8000u);
        key[1][j] = (b & 0x8000u) ? (~b & 0xffffu) : (b | 0x8000u);
    }
    int mi = (int)ceilf(kvv);
    mi = mi < 1 ? 1 : (mi > QDIM ? QDIM : mi);
    const unsigned m = (unsigned)mi;
    unsigned* h = hist[w];
    unsigned* hg = h + (lane >> 3) * KH_GS;   // this lane's sub-histogram

    hist_zero(h, lane);
    __threadfence_block();
#pragma unroll
    for (int c = 0; c < 2; c++)
#pragma unroll
        for (int j = 0; j < 8; j++)
            atomicAdd(&hg[key[c][j] >> 8], 1u);
    __threadfence_block();
    unsigned hi, rem1;
    suffix_pick(h, lane, m, hi, rem1);

    hist_zero(h, lane);
    __threadfence_block();
#pragma unroll
    for (int c = 0; c < 2; c++)
#pragma unroll
        for (int j = 0; j < 8; j++)
            if ((key[c][j] >> 8) == hi) atomicAdd(&hg[key[c][j] & 255u], 1u);
    __threadfence_block();
    unsigned lo, need;
    suffix_pick(h, lane, rem1, lo, need);

    const unsigned um = (hi << 8) | lo;

    unsigned cnt0 = 0, cnt1 = 0;
#pragma unroll
    for (int j = 0; j < 8; j++) { cnt0 += (key[0][j] == um); cnt1 += (key[1][j] == um); }
    unsigned pack = cnt0 | (cnt1 << 16);
    unsigned incl = pack;
#pragma unroll
    for (int off = 1; off < 64; off <<= 1) {
        unsigned t = __shfl_up(incl, off);
        if (lane >= off) incl += t;
    }
    unsigned excl = incl - pack;
    unsigned tot0 = __shfl(incl, 63) & 0xffffu;
    unsigned r0 = excl & 0xffffu;
    unsigned r1 = tot0 + (excl >> 16);

    float of[2][8];
    u16x8 mb0, mb1;
#pragma unroll
    for (int j = 0; j < 8; j++) {
        unsigned kv_ = key[0][j];
        bool s;
        if (kv_ > um) s = true;
        else if (kv_ == um) { s = (r0 < need); r0++; }
        else s = false;
        of[0][j] = s ? 1.0f : 0.0f;
        mb0[j] = s ? (u16)0x3F80 : (u16)0;
    }
#pragma unroll
    for (int j = 0; j < 8; j++) {
        unsigned kv_ = key[1][j];
        bool s;
        if (kv_ > um) s = true;
        else if (kv_ == um) { s = (r1 < need); r1++; }
        else s = false;
        of[1][j] = s ? 1.0f : 0.0f;
        mb1[j] = s ? (u16)0x3F80 : (u16)0;
    }
    *(float4*)(mfp + lane * 8)           = make_float4(of[0][0], of[0][1], of[0][2], of[0][3]);
    *(float4*)(mfp + lane * 8 + 4)       = make_float4(of[0][4], of[0][5], of[0][6], of[0][7]);
    *(float4*)(mfp + 512 + lane * 8)     = make_float4(of[1][0], of[1][1], of[1][2], of[1][3]);
    *(float4*)(mfp + 512 + lane * 8 + 4) = make_float4(of[1][4], of[1][5], of[1][6], of[1][7]);
    *(u16x8*)(rp + lane * 8)       = mb0;
    *(u16x8*)(rp + 512 + lane * 8) = mb1;
}

// ---------------------------------------------------------------------------
extern "C" void kernel_launch(void* const* d_in, const int* in_sizes, int n_in,
                              void* d_out, int out_size, void* d_ws, size_t ws_size,
                              hipStream_t stream) {
    const float* x     = (const float*)d_in[0];
    const float* W_e1  = (const float*)d_in[1];
    const float* b_e1  = (const float*)d_in[2];
    const float* W_e2  = (const float*)d_in[3];
    const float* b_e2  = (const float*)d_in[4];
    const float* W_cb  = (const float*)d_in[5];
    const float* W_d1  = (const float*)d_in[6];
    const float* b_d1  = (const float*)d_in[7];
    const float* W_d2  = (const float*)d_in[8];
    const float* b_d2  = (const float*)d_in[9];
    const float* W_k1  = (const float*)d_in[10];
    const float* b_k1  = (const float*)d_in[11];
    const float* W_k2  = (const float*)d_in[12];
    const float* b_k2  = (const float*)d_in[13];
    const float* W_k3  = (const float*)d_in[14];
    const float* b_k3  = (const float*)d_in[15];
    const float* k_scl = (const float*)d_in[16];

    float* out   = (float*)d_out;
    float* recon = out;
    float* maskf = out + OUT_KHOT_OFF;
    float* scl   = out + OUT_SCALAR_OFF;
    float* kout  = out + OUT_K_OFF;

    char* ws = (char*)d_ws;
    bf16* wb_k1  = (bf16*)(ws + WS_WK1);
    bf16* wb_e2  = (bf16*)(ws + WS_WE2);
    bf16* wb_cb  = (bf16*)(ws + WS_WCB);
    bf16* wb_d1  = (bf16*)(ws + WS_WD1);
    bf16* wb_d2  = (bf16*)(ws + WS_WD2);
    bf16* wb_k2  = (bf16*)(ws + WS_WK2);
    bf16* wstk   = (bf16*)(ws + WS_WSTK);
    float* bstk  = (float*)(ws + WS_BSTK);
    float* kpart = (float*)(ws + WS_KPART);
    bf16* bufA   = (bf16*)(ws + WS_BUFA);
    bf16* bufB   = (bf16*)(ws + WS_BUFB);
    bf16* bufC   = (bf16*)(ws + WS_BUFC);
    bf16* bufX   = (bf16*)(ws + WS_BUFX);
    bf16* we2t   = (bf16*)(ws + WS_WE2T);
    bf16* wcomb2 = (bf16*)(ws + WS_WCOMB2);
    float* bconst = (float*)(ws + WS_BCONST);

    const dim3 blk(256);
    const dim3 blk512(512);
    const int FULL = 1 << 30;

    // prep: conversions (incl. x->bf16) + stacked W/b + We2T + bconst + kpart
    cvt_kernel<<<dim3(CVT_GRID), blk, 0, stream>>>(
        W_e1, W_e2, W_cb, W_d1, W_d2, W_k1, W_k2, b_e1, b_e2, b_k1, x, ws);

    // Wcomb2 (16 blocks, overlapped under E1) + E1||K1a (2048, swizzled)
    fusedA_kernel<<<dim3(2064), blk, 0, stream>>>(
        bufX, wstk, bstk, bufA, wb_k1 + 256, we2t, wcomb2);

    // E2 + K1b' merged (128² 2-barrier, 3072 blocks — R7-best)
    fusedB_kernel<<<dim3(3072), blk, 0, stream>>>(
        bufA, wb_e2, b_e2, bufB, wcomb2, bconst, bufC);

    // K2+kdot: kpart[row] += relu(hk1 @ Wk2^T + b_k2) . w3  (128², 1024 blk)
    mgemm<2, 1, 0, 0, 4><<<dim3(1024), blk, 0, stream>>>(
        bufC, nullptr, wb_k2, b_k2, W_k3, kpart, 512, 512, 512, 512, 0, FULL);

    // khot (+kfinal): logits -> fp32 mask (d_out) + bf16 mask; k -> kout/scl
    khot_kernel<<<dim3(Bn / 4), blk, 0, stream>>>(
        (u16*)bufB, kpart, b_k3, k_scl, maskf, kout, scl);

    // FUSED decoder: CB -> D1 -> D2, q/hd1 in LDS (256 blocks = 1 round)
    decoder_kernel<<<dim3(256), blk512, 0, stream>>>(
        bufB, wb_cb, kout, wb_d1, b_d1, wb_d2, b_d2, recon);
}